// Round 18
// baseline (422.981 us; speedup 1.0000x reference)
//
#include <hip/hip_runtime.h>
#include <math.h>

#define BB 4
#define NN 1024
#define DIMM 1024
#define HHH 16
#define DHH 64
#define BN 4096            // B*N rows
#define EPS_LN 1e-6f

typedef __bf16 bf16_t;
typedef __bf16 bf16x8 __attribute__((ext_vector_type(8)));
typedef __bf16 bf16x4 __attribute__((ext_vector_type(4)));
typedef float f32x4 __attribute__((ext_vector_type(4)));
typedef float f32x16 __attribute__((ext_vector_type(16)));
#define MFMA16(a, b, c) __builtin_amdgcn_mfma_f32_16x16x32_bf16(a, b, c, 0, 0, 0)
#define MFMA32(a, b, c) __builtin_amdgcn_mfma_f32_32x32x16_bf16(a, b, c, 0, 0, 0)
#define AS1 __attribute__((address_space(1)))
#define AS3 __attribute__((address_space(3)))

__device__ inline unsigned pk2(float a, float b) {
  union { bf16_t h[2]; unsigned u; } c;
  c.h[0] = (bf16_t)a; c.h[1] = (bf16_t)b;
  return c.u;
}
union U16 { uint4 u; bf16x8 v; };

// ============================================================
// pack_x3: Ax3[4096][3072] = bf16([xr+xi | xi | xr])  (3-mult A-operands)
// ============================================================
__global__ __launch_bounds__(256) void pack_x3(
    const float* __restrict__ xr, const float* __restrict__ xi,
    bf16_t* __restrict__ out)
{
  int t = blockIdx.x * 256 + threadIdx.x;
  size_t e = (size_t)t * 8;
  int row = (int)(e / 3072), col = (int)(e % 3072);
  bf16x8 o;
  if (col < 1024) {
    const float* pr = xr + (size_t)row * 1024 + col;
    const float* pi = xi + (size_t)row * 1024 + col;
    float4 a0 = *(const float4*)pr, a1 = *(const float4*)(pr + 4);
    float4 b0 = *(const float4*)pi, b1 = *(const float4*)(pi + 4);
    o[0] = (bf16_t)(a0.x + b0.x); o[1] = (bf16_t)(a0.y + b0.y);
    o[2] = (bf16_t)(a0.z + b0.z); o[3] = (bf16_t)(a0.w + b0.w);
    o[4] = (bf16_t)(a1.x + b1.x); o[5] = (bf16_t)(a1.y + b1.y);
    o[6] = (bf16_t)(a1.z + b1.z); o[7] = (bf16_t)(a1.w + b1.w);
  } else {
    const float* src = (col < 2048) ? (xi + (size_t)row * 1024 + col - 1024)
                                    : (xr + (size_t)row * 1024 + col - 2048);
    float4 a0 = *(const float4*)src, a1 = *(const float4*)(src + 4);
    o[0] = (bf16_t)a0.x; o[1] = (bf16_t)a0.y; o[2] = (bf16_t)a0.z; o[3] = (bf16_t)a0.w;
    o[4] = (bf16_t)a1.x; o[5] = (bf16_t)a1.y; o[6] = (bf16_t)a1.z; o[7] = (bf16_t)a1.w;
  }
  *(bf16x8*)(out + e) = o;
}

// ============================================================
// pack_w9: W9[p*3+j][1024][1024], j=0: Wr, j=1: Wr+Wi, j=2: Wi-Wr.
// grid (512, 9).
// ============================================================
__global__ __launch_bounds__(256) void pack_w9(
    const float* __restrict__ Wqr, const float* __restrict__ Wqi,
    const float* __restrict__ Wkr, const float* __restrict__ Wki,
    const float* __restrict__ Wvr, const float* __restrict__ Wvi,
    bf16_t* __restrict__ W9)
{
  const int bz = blockIdx.y;
  const int p = bz / 3, j = bz - p * 3;
  const float* Wr = (p == 0) ? Wqr : (p == 1) ? Wkr : Wvr;
  const float* Wi = (p == 0) ? Wqi : (p == 1) ? Wki : Wvi;
  int t = blockIdx.x * 256 + threadIdx.x;
  size_t e = (size_t)t * 8;
  const float* pr = Wr + e;
  const float* pi = Wi + e;
  float4 a0 = *(const float4*)pr, a1 = *(const float4*)(pr + 4);
  float4 b0 = *(const float4*)pi, b1 = *(const float4*)(pi + 4);
  float v0[8] = {a0.x, a0.y, a0.z, a0.w, a1.x, a1.y, a1.z, a1.w};
  float v1[8] = {b0.x, b0.y, b0.z, b0.w, b1.x, b1.y, b1.z, b1.w};
  bf16x8 o;
#pragma unroll
  for (int k = 0; k < 8; ++k) {
    float v = (j == 0) ? v0[k] : (j == 1) ? (v0[k] + v1[k]) : (v1[k] - v0[k]);
    o[k] = (bf16_t)v;
  }
  *(bf16x8*)(W9 + (size_t)bz * 1048576 + e) = o;
}

// ============================================================
// pack_w: O-projection augmented weights [Wr|-Wi ; Wi|Wr] + bias.
// ============================================================
__global__ __launch_bounds__(256) void pack_w(
    const float* __restrict__ Wr, const float* __restrict__ Wi,
    const float* __restrict__ br, const float* __restrict__ bi,
    bf16_t* __restrict__ Wcat, float* __restrict__ bcat)
{
  int t = blockIdx.x * 256 + threadIdx.x;
  size_t e = (size_t)t * 8;
  int row = (int)(e >> 11), col = (int)(e & 2047);
  const float* src;
  float sgn = 1.f;
  if (row < 1024) {
    if (col < 1024) src = Wr + (size_t)row * 1024 + col;
    else          { src = Wi + (size_t)row * 1024 + col - 1024; sgn = -1.f; }
  } else {
    int r2 = row - 1024;
    if (col < 1024) src = Wi + (size_t)r2 * 1024 + col;
    else            src = Wr + (size_t)r2 * 1024 + col - 1024;
  }
  float4 a = *(const float4*)src;
  float4 b = *(const float4*)(src + 4);
  bf16x8 o;
  o[0] = (bf16_t)(sgn * a.x); o[1] = (bf16_t)(sgn * a.y);
  o[2] = (bf16_t)(sgn * a.z); o[3] = (bf16_t)(sgn * a.w);
  o[4] = (bf16_t)(sgn * b.x); o[5] = (bf16_t)(sgn * b.y);
  o[6] = (bf16_t)(sgn * b.z); o[7] = (bf16_t)(sgn * b.w);
  *(bf16x8*)(Wcat + e) = o;
  if (e < 2048) {
#pragma unroll
    for (int j = 0; j < 8; ++j) {
      int n = (int)e + j;
      bcat[n] = (n < 1024) ? br[n] : bi[n - 1024];
    }
  }
}

// ============================================================
// gemm_k3: batched 3-mult GEMMs. grid (8, 32, 9); bz = p*3 + j.
// m_j[4096][1024] = A_j[4096][1024](lda 3072, col off j*1024)
//                   @ W9[bz][1024][1024]^T.  K=1024, m97 2-phase.
// Output raw (no bias) into C9[4096][9216] at p*3072 + j*1024.
// ============================================================
__global__ __launch_bounds__(256) void gemm_k3(
    const bf16_t* __restrict__ Ax3, const bf16_t* __restrict__ W9,
    bf16_t* __restrict__ C9)
{
  __shared__ bf16_t sA[128 * 64];
  __shared__ bf16_t sB[128 * 64];
  const int tid = threadIdx.x;
  const int w = tid >> 6, l = tid & 63;
  const int lo4 = l & 15, hi = l >> 4;
  const int wr = w >> 1, wc = w & 1;
  const int row0 = blockIdx.y * 128, col0 = blockIdx.x * 128;
  const int bz = blockIdx.z;
  const int p = bz / 3, j = bz - p * 3;

  const bf16_t* Abase = Ax3 + (size_t)j * 1024;
  const bf16_t* Bbase = W9 + (size_t)bz * 1048576;

  const int srow = (l >> 3);
  const int scol = (l & 7) * 8;
  const bf16_t* gA[4];
  const bf16_t* gB[4];
#pragma unroll
  for (int i = 0; i < 4; ++i) {
    int r = (w * 4 + i) * 8 + srow;
    gA[i] = Abase + (size_t)(row0 + r) * 3072 + scol;
    gB[i] = Bbase + (size_t)(col0 + r) * 1024 + scol;
  }

  f32x4 acc[4][4] = {};
  for (int k0 = 0; k0 < 1024; k0 += 64) {
    __syncthreads();
#pragma unroll
    for (int i = 0; i < 4; ++i) {
      __builtin_amdgcn_global_load_lds((const AS1 void*)(gA[i] + k0),
                                       (AS3 void*)&sA[(w * 4 + i) * 512], 16, 0, 0);
      __builtin_amdgcn_global_load_lds((const AS1 void*)(gB[i] + k0),
                                       (AS3 void*)&sB[(w * 4 + i) * 512], 16, 0, 0);
    }
    __syncthreads();
#pragma unroll
    for (int kk = 0; kk < 2; ++kk) {
      bf16x8 am[4], bn[4];
#pragma unroll
      for (int i = 0; i < 4; ++i)
        am[i] = *(const bf16x8*)&sA[(wr * 64 + i * 16 + lo4) * 64 + kk * 32 + hi * 8];
#pragma unroll
      for (int jf = 0; jf < 4; ++jf)
        bn[jf] = *(const bf16x8*)&sB[(wc * 64 + jf * 16 + lo4) * 64 + kk * 32 + hi * 8];
#pragma unroll
      for (int i = 0; i < 4; ++i)
#pragma unroll
        for (int jf = 0; jf < 4; ++jf)
          acc[i][jf] = MFMA16(am[i], bn[jf], acc[i][jf]);
    }
  }
  bf16_t* Cb = C9 + (size_t)p * 3072 + (size_t)j * 1024;
  const int colg0 = col0 + wc * 64;
#pragma unroll
  for (int i = 0; i < 4; ++i) {
#pragma unroll
    for (int jf = 0; jf < 4; ++jf) {
#pragma unroll
      for (int r = 0; r < 4; ++r) {
        int rowg = row0 + wr * 64 + i * 16 + hi * 4 + r;
        Cb[(size_t)rowg * 9216 + colg0 + jf * 16 + lo4] = (bf16_t)acc[i][jf][r];
      }
    }
  }
}

// ============================================================
// O-projection GEMM (m97 2-phase known-good, fp32 split output).
// ============================================================
__global__ __launch_bounds__(256) void gemm_bf16(
    const bf16_t* __restrict__ A, const bf16_t* __restrict__ Bt,
    const float* __restrict__ bias,
    float* __restrict__ Cr, float* __restrict__ Ci, int ldc)
{
  __shared__ bf16_t sA[128 * 64];
  __shared__ bf16_t sB[128 * 64];
  const int tid = threadIdx.x;
  const int w = tid >> 6, l = tid & 63;
  const int lo4 = l & 15, hi = l >> 4;
  const int wr = w >> 1, wc = w & 1;
  const int row0 = blockIdx.y * 128, col0 = blockIdx.x * 128;

  const int srow = (l >> 3);
  const int scol = (l & 7) * 8;
  const bf16_t* gA[4];
  const bf16_t* gB[4];
#pragma unroll
  for (int i = 0; i < 4; ++i) {
    int r = (w * 4 + i) * 8 + srow;
    gA[i] = A  + (size_t)(row0 + r) * 2048 + scol;
    gB[i] = Bt + (size_t)(col0 + r) * 2048 + scol;
  }

  f32x4 acc[4][4] = {};
  for (int k0 = 0; k0 < 2048; k0 += 64) {
    __syncthreads();
#pragma unroll
    for (int i = 0; i < 4; ++i) {
      __builtin_amdgcn_global_load_lds((const AS1 void*)(gA[i] + k0),
                                       (AS3 void*)&sA[(w * 4 + i) * 512], 16, 0, 0);
      __builtin_amdgcn_global_load_lds((const AS1 void*)(gB[i] + k0),
                                       (AS3 void*)&sB[(w * 4 + i) * 512], 16, 0, 0);
    }
    __syncthreads();
#pragma unroll
    for (int kk = 0; kk < 2; ++kk) {
      bf16x8 am[4], bn[4];
#pragma unroll
      for (int i = 0; i < 4; ++i)
        am[i] = *(const bf16x8*)&sA[(wr * 64 + i * 16 + lo4) * 64 + kk * 32 + hi * 8];
#pragma unroll
      for (int j = 0; j < 4; ++j)
        bn[j] = *(const bf16x8*)&sB[(wc * 64 + j * 16 + lo4) * 64 + kk * 32 + hi * 8];
#pragma unroll
      for (int i = 0; i < 4; ++i)
#pragma unroll
        for (int j = 0; j < 4; ++j)
          acc[i][j] = MFMA16(am[i], bn[j], acc[i][j]);
    }
  }
  const int colg0 = col0 + wc * 64;
  float* Cp = (colg0 < 1024) ? Cr : Ci;
  const int cb = colg0 & 1023;
#pragma unroll
  for (int i = 0; i < 4; ++i) {
#pragma unroll
    for (int j = 0; j < 4; ++j) {
      float bv = bias[colg0 + j * 16 + lo4];
#pragma unroll
      for (int r = 0; r < 4; ++r) {
        int rowg = row0 + wr * 64 + i * 16 + hi * 4 + r;
        Cp[(size_t)rowg * ldc + cb + j * 16 + lo4] = acc[i][j][r] + bv;
      }
    }
  }
}

// ============================================================
// ln_stats3m: stats over 3-mult-combined rows.
// re = m1 - m2 + br[c], im = m1 + m3 + bi[c].  grid (4096, 3).
// ============================================================
__global__ __launch_bounds__(256) void ln_stats3m(
    const bf16_t* __restrict__ C9, float2* __restrict__ st,
    const float* __restrict__ bqr, const float* __restrict__ bqi,
    const float* __restrict__ bkr, const float* __restrict__ bki,
    const float* __restrict__ bvr, const float* __restrict__ bvi)
{
  __shared__ float red[8];
  const int row = blockIdx.x;
  const int p = blockIdx.y;
  const int tid = threadIdx.x;
  const float* br = (p == 0) ? bqr : (p == 1) ? bkr : bvr;
  const float* bi = (p == 0) ? bqi : (p == 1) ? bki : bvi;
  const bf16_t* base = C9 + (size_t)row * 9216 + (size_t)p * 3072 + tid * 4;
  bf16x4 m1 = *(const bf16x4*)base;
  bf16x4 m2 = *(const bf16x4*)(base + 1024);
  bf16x4 m3 = *(const bf16x4*)(base + 2048);
  float s = 0.f, s2 = 0.f;
#pragma unroll
  for (int t = 0; t < 4; ++t) {
    int c = tid * 4 + t;
    float re = (float)m1[t] - (float)m2[t] + br[c];
    float im = (float)m1[t] + (float)m3[t] + bi[c];
    float mg = sqrtf(re * re + im * im);
    s += mg; s2 += mg * mg;
  }
#pragma unroll
  for (int o = 32; o; o >>= 1) { s += __shfl_down(s, o); s2 += __shfl_down(s2, o); }
  if ((tid & 63) == 0) { red[tid >> 6] = s; red[4 + (tid >> 6)] = s2; }
  __syncthreads();
  if (tid == 0) {
    float S = red[0] + red[1] + red[2] + red[3];
    float S2 = red[4] + red[5] + red[6] + red[7];
    float mean = S * (1.f / DIMM);
    float var = S2 * (1.f / DIMM) - mean * mean;
    st[(size_t)p * 4096 + row] = make_float2(mean, rsqrtf(var + EPS_LN));
  }
}

// ============================================================
// 1024-pt RADIX-4 DIF FFT v3 — bf16 in/out.
// imode 2 (new): 3-mult input — inR points at the m-plane base;
//   m1 at +0, m2 at +1024, m3 at +2048; re=m1-m2+br, im=m1+m3+bi,
//   then fused LN (stats required).
// imode 1: n-contiguous input (iFFT).  omode 0/1/2 as before.
// ============================================================
#define LIDX(d_, c_) (((d_) << 10) + ((c_) ^ (((c_) >> 5) & 31) ^ (((d_) & 7) << 2)))

__global__ __launch_bounds__(512) void fft_kernel(
    const bf16_t* __restrict__ inR, const bf16_t* __restrict__ inI,
    bf16_t* __restrict__ outR, bf16_t* __restrict__ outI,
    long in_sb, int in_sh, int in_sn, int in_sd,
    int out_sb, int out_sh, int out_sn,
    float sign, float oscale, int imode, int omode,
    const float2* __restrict__ stats,
    const float* __restrict__ gamma, const float* __restrict__ beta,
    const float* __restrict__ biasr, const float* __restrict__ biasi)
{
  __shared__ float lr[8 * 1024], li[8 * 1024];
  __shared__ float2 tw[1024];
  const int tid = threadIdx.x;
  const int dc = blockIdx.x & 7;
  const int bh = blockIdx.x >> 3;
  const int b = bh >> 4, h = bh & 15;
  const bf16_t* bR = inR + (size_t)b * in_sb + (size_t)h * in_sh;
  const bf16_t* bI = inI + (size_t)b * in_sb + (size_t)h * in_sh;
#pragma unroll
  for (int t = tid; t < 1024; t += 512) {
    float ang = sign * 3.14159265358979323846f * (float)t * (1.f / 512.f);
    float sn, cs;
    __sincosf(ang, &sn, &cs);
    tw[t] = make_float2(cs, sn);
  }
  if (imode == 2) {
    float gg[8], bb[8], brv[8], biv[8];
#pragma unroll
    for (int ds = 0; ds < 8; ++ds) {
      int dim = h * DHH + dc * 8 + ds;
      gg[ds] = gamma[dim];  bb[ds] = beta[dim];
      brv[ds] = biasr[dim]; biv[ds] = biasi[dim];
    }
#pragma unroll
    for (int rep = 0; rep < 2; ++rep) {
      int n = tid + rep * 512;
      const bf16_t* pb = bR + (size_t)n * in_sn + dc * 8;
      bf16x8 m1 = *(const bf16x8*)pb;
      bf16x8 m2 = *(const bf16x8*)(pb + 1024);
      bf16x8 m3 = *(const bf16x8*)(pb + 2048);
      float2 stv = stats[b * NN + n];
#pragma unroll
      for (int ds = 0; ds < 8; ++ds) {
        float re = (float)m1[ds] - (float)m2[ds] + brv[ds];
        float im = (float)m1[ds] + (float)m3[ds] + biv[ds];
        float mag = sqrtf(re * re + im * im);
        float nm = (mag - stv.x) * stv.y * gg[ds] + bb[ds];
        if (mag > 0.f) { float sc = nm / mag; re *= sc; im *= sc; }
        else           { re = nm; im = 0.f; }
        int ax = LIDX(ds, n);
        lr[ax] = re;
        li[ax] = im;
      }
    }
  } else {
    const int ds = tid & 7, nb = tid >> 3;
    const bf16_t* pR = bR + (size_t)(dc * 8 + ds) * in_sd + nb * 16;
    const bf16_t* pI = bI + (size_t)(dc * 8 + ds) * in_sd + nb * 16;
    bf16x8 a0 = *(const bf16x8*)pR, a1 = *(const bf16x8*)(pR + 8);
    bf16x8 b0 = *(const bf16x8*)pI, b1 = *(const bf16x8*)(pI + 8);
#pragma unroll
    for (int k = 0; k < 8; ++k) {
      int c = nb * 16 + k;
      lr[LIDX(ds, c)] = (float)a0[k];       li[LIDX(ds, c)] = (float)b0[k];
      lr[LIDX(ds, c + 8)] = (float)a1[k];   li[LIDX(ds, c + 8)] = (float)b1[k];
    }
  }
  __syncthreads();
  const int dsub = tid & 7;
  const int jb = tid >> 3;
  int lq2 = 8;
  for (int st = 0; st < 5; ++st) {
    const int qtr = 1 << lq2;
    const int tmul = 1 << (2 * st);
    for (int jt = 0; jt < 4; ++jt) {
      int j = jb + jt * 64;
      int o = j & (qtr - 1);
      int i0 = ((j >> lq2) << (lq2 + 2)) + o;
      int a0 = LIDX(dsub, i0);
      int a1 = LIDX(dsub, i0 + qtr);
      int a2 = LIDX(dsub, i0 + 2 * qtr);
      int a3 = LIDX(dsub, i0 + 3 * qtr);
      float x0r = lr[a0], x0i = li[a0];
      float x1r = lr[a1], x1i = li[a1];
      float x2r = lr[a2], x2i = li[a2];
      float x3r = lr[a3], x3i = li[a3];
      float ar = x0r + x2r, ai2 = x0i + x2i;
      float br = x0r - x2r, bi  = x0i - x2i;
      float cr = x1r + x3r, ci  = x1i + x3i;
      float dr = x1r - x3r, di  = x1i - x3i;
      float2 t1 = tw[o * tmul];
      float2 t2 = tw[2 * o * tmul];
      float2 t3 = tw[3 * o * tmul];
      lr[a0] = ar + cr;  li[a0] = ai2 + ci;
      float u1r = br - sign * di, u1i = bi + sign * dr;
      lr[a1] = u1r * t1.x - u1i * t1.y;  li[a1] = u1r * t1.y + u1i * t1.x;
      float u2r = ar - cr, u2i = ai2 - ci;
      lr[a2] = u2r * t2.x - u2i * t2.y;  li[a2] = u2r * t2.y + u2i * t2.x;
      float u3r = br + sign * di, u3i = bi - sign * dr;
      lr[a3] = u3r * t3.x - u3i * t3.y;  li[a3] = u3r * t3.y + u3i * t3.x;
    }
    __syncthreads();
    lq2 -= 2;
  }
  bf16_t* oRb = outR + (size_t)b * out_sb + (size_t)h * out_sh;
  bf16_t* oIb = outI + (size_t)b * out_sb + (size_t)h * out_sh;
#pragma unroll
  for (int rep = 0; rep < 2; ++rep) {
    int n = tid + rep * 512;
    int rv2 = __brev((unsigned)n) >> 22;
    int p = ((rv2 & 0x155) << 1) | ((rv2 >> 1) & 0x155);
    float fr[8], fi[8];
#pragma unroll
    for (int ds = 0; ds < 8; ++ds) {
      fr[ds] = lr[LIDX(ds, p)] * oscale;
      fi[ds] = li[LIDX(ds, p)] * oscale;
    }
    if (omode == 1) {
      size_t tb = (size_t)(n >> 5) * 4096;
#pragma unroll
      for (int ds = 0; ds < 8; ++ds) {
        int dch = dc * 8 + ds;
        size_t ga = tb + (size_t)dch * 32 + ((n & 31) ^ (((dch >> 1) & 3) << 3));
        oRb[ga] = (bf16_t)fr[ds];
        oIb[ga] = (bf16_t)fi[ds];
      }
    } else {
      int cb = dc * 8;
      if (omode == 2) cb = (dc ^ (n & 7)) * 8;
      bf16x8 v0, w0;
#pragma unroll
      for (int k = 0; k < 8; ++k) {
        v0[k] = (bf16_t)fr[k];
        w0[k] = (bf16_t)fi[k];
      }
      size_t gb = (size_t)n * out_sn + cb;
      *(bf16x8*)(oRb + gb) = v0;
      *(bf16x8*)(oIb + gb) = w0;
    }
  }
}

// ============================================================
// Flash attention v7 (unchanged control).
// ============================================================
__global__ __launch_bounds__(256, 2) void fattn(
    const bf16_t* __restrict__ Qf, const bf16_t* __restrict__ Kfs,
    const bf16_t* __restrict__ Vfs, bf16_t* __restrict__ OT)
{
  __shared__ bf16_t K3[3][4096];
  __shared__ bf16_t V3[3][4096];
  const int tid = threadIdx.x;
  const int w = tid >> 6, l = tid & 63;
  const int lq = l & 31;
  const int h = l >> 5;
  const int i = blockIdx.x;
  const int j = i >> 3;
  const int bh = (i & 7) * 8 + (j >> 3);
  const int q0 = (j & 7) * 128 + w * 32;

  bf16x8 bq[8];
  const bf16_t* qp = Qf + ((size_t)bh * NN + q0 + lq) * 128 + h * 8;
#pragma unroll
  for (int kk = 0; kk < 8; ++kk) bq[kk] = *(const bf16x8*)(qp + kk * 16);

  f32x16 o[4] = {};
  float m = -3e38f, ln = 0.f;

  const bf16_t* kg = Kfs + (size_t)bh * 131072 + w * 1024 + l * 8;
  const bf16_t* vg = Vfs + (size_t)bh * 131072 + w * 1024 + l * 8;
  const int kswz = (lq & 7) << 3;
  const int vswz = ((lq >> 1) & 3) << 3;

#pragma unroll
  for (int tt = 0; tt < 2; ++tt) {
    const bf16_t* kt = kg + (size_t)tt * 4096;
    const bf16_t* vt = vg + (size_t)tt * 4096;
#pragma unroll
    for (int ii = 0; ii < 2; ++ii) {
      __builtin_amdgcn_global_load_lds((const AS1 void*)(kt + ii * 512),
                                       (AS3 void*)&K3[tt][w * 1024 + ii * 512], 16, 0, 0);
      __builtin_amdgcn_global_load_lds((const AS1 void*)(vt + ii * 512),
                                       (AS3 void*)&V3[tt][w * 1024 + ii * 512], 16, 0, 0);
    }
  }
  asm volatile("s_waitcnt vmcnt(4)" ::: "memory");
  __builtin_amdgcn_s_barrier();
  __builtin_amdgcn_sched_barrier(0);

  int cur = 0;
  for (int t = 0; t < 32; ++t) {
    if (t < 30) {
      int nb = cur + 2; if (nb >= 3) nb -= 3;
      const bf16_t* kt = kg + (size_t)(t + 2) * 4096;
      const bf16_t* vt = vg + (size_t)(t + 2) * 4096;
#pragma unroll
      for (int ii = 0; ii < 2; ++ii) {
        __builtin_amdgcn_global_load_lds((const AS1 void*)(kt + ii * 512),
                                         (AS3 void*)&K3[nb][w * 1024 + ii * 512], 16, 0, 0);
        __builtin_amdgcn_global_load_lds((const AS1 void*)(vt + ii * 512),
                                         (AS3 void*)&V3[nb][w * 1024 + ii * 512], 16, 0, 0);
      }
    }

    f32x16 s = {};
#pragma unroll
    for (int kk = 0; kk < 8; ++kk) {
      bf16x8 ak = *(const bf16x8*)&K3[cur][lq * 128 + ((kk * 16 + h * 8) ^ kswz)];
      s = MFMA32(ak, bq[kk], s);
    }

    float pmax = s[0];
#pragma unroll
    for (int r = 1; r < 16; ++r) pmax = fmaxf(pmax, s[r]);
    pmax = fmaxf(pmax, __shfl_xor(pmax, 32));
    if (!__all(pmax - m <= 8.f)) {
      float mnew = fmaxf(m, pmax);
      float alpha = __expf(m - mnew);
      m = mnew;
      ln *= alpha;
#pragma unroll
      for (int db = 0; db < 4; ++db)
#pragma unroll
        for (int r = 0; r < 16; ++r) o[db][r] *= alpha;
    }
    float pf[16];
    float rs = 0.f;
#pragma unroll
    for (int r = 0; r < 16; ++r) { pf[r] = __expf(s[r] - m); rs += pf[r]; }
    rs += __shfl_xor(rs, 32);
    ln += rs;

    unsigned pw[8];
#pragma unroll
    for (int ii = 0; ii < 8; ++ii) pw[ii] = pk2(pf[2 * ii], pf[2 * ii + 1]);
    unsigned r0 = (unsigned)__shfl_xor((int)(h ? pw[0] : pw[2]), 32);
    unsigned r1 = (unsigned)__shfl_xor((int)(h ? pw[1] : pw[3]), 32);
    unsigned r2 = (unsigned)__shfl_xor((int)(h ? pw[4] : pw[6]), 32);
    unsigned r3 = (unsigned)__shfl_xor((int)(h ? pw[5] : pw[7]), 32);
    U16 bp0, bp1;
    bp0.u.x = h ? r0 : pw[0];  bp0.u.y = h ? r1 : pw[1];
    bp0.u.z = h ? pw[2] : r0;  bp0.u.w = h ? pw[3] : r1;
    bp1.u.x = h ? r2 : pw[4];  bp1.u.y = h ? r3 : pw[5];
    bp1.u.z = h ? pw[6] : r2;  bp1.u.w = h ? pw[7] : r3;

#pragma unroll
    for (int db = 0; db < 4; ++db) {
      int r = db * 32 + lq;
      bf16x8 av0 = *(const bf16x8*)&V3[cur][r * 32 + ((h * 8) ^ vswz)];
      bf16x8 av1 = *(const bf16x8*)&V3[cur][r * 32 + ((16 + h * 8) ^ vswz)];
      o[db] = MFMA32(av0, bp0.v, o[db]);
      o[db] = MFMA32(av1, bp1.v, o[db]);
    }

    if (t < 31) {
      if (t < 30) asm volatile("s_waitcnt vmcnt(4)" ::: "memory");
      else        asm volatile("s_waitcnt vmcnt(0)" ::: "memory");
      __builtin_amdgcn_s_barrier();
      __builtin_amdgcn_sched_barrier(0);
    }
    cur = (cur == 2) ? 0 : cur + 1;
  }

  float inv = 1.f / ln;
  const size_t otb = (size_t)bh * 128 * NN + q0 + lq;
#pragma unroll
  for (int db = 0; db < 4; ++db)
#pragma unroll
    for (int r = 0; r < 16; ++r) {
      int dl = (r & 3) + 8 * (r >> 2) + 4 * h;
      OT[otb + (size_t)(db * 32 + dl) * NN] = (bf16_t)(o[db][r] * inv);
    }
}

// ============================================================
// Host-side orchestration
// ============================================================
extern "C" void kernel_launch(void* const* d_in, const int* in_sizes, int n_in,
                              void* d_out, int out_size, void* d_ws, size_t ws_size,
                              hipStream_t stream) {
  const float* xr   = (const float*)d_in[0];
  const float* xi   = (const float*)d_in[1];
  const float* Wqr  = (const float*)d_in[2];
  const float* Wqi  = (const float*)d_in[3];
  const float* bqr  = (const float*)d_in[4];
  const float* bqi  = (const float*)d_in[5];
  const float* Wkr  = (const float*)d_in[6];
  const float* Wki  = (const float*)d_in[7];
  const float* bkr  = (const float*)d_in[8];
  const float* bki  = (const float*)d_in[9];
  const float* Wvr  = (const float*)d_in[10];
  const float* Wvi  = (const float*)d_in[11];
  const float* bvr  = (const float*)d_in[12];
  const float* bvi  = (const float*)d_in[13];
  const float* Wor  = (const float*)d_in[14];
  const float* Woi  = (const float*)d_in[15];
  const float* bor  = (const float*)d_in[16];
  const float* boi  = (const float*)d_in[17];
  const float* gq   = (const float*)d_in[18];
  const float* beq  = (const float*)d_in[19];
  const float* gk   = (const float*)d_in[20];
  const float* bek  = (const float*)d_in[21];
  const float* gv   = (const float*)d_in[22];
  const float* bev  = (const float*)d_in[23];

  char* wp = (char*)d_ws;
  bf16_t* Ax3   = (bf16_t*)wp;  wp += (size_t)4096 * 3072 * 2;     // 25.2 MB
  bf16_t* W9    = (bf16_t*)wp;  wp += (size_t)9 * 1048576 * 2;     // 18.9 MB
  float*  bcatO = (float*)wp;   wp += (size_t)2048 * 4;
  float2* lnst3 = (float2*)wp;  wp += (size_t)3 * 4096 * 8;
  bf16_t* C9    = (bf16_t*)wp;  wp += (size_t)4096 * 9216 * 2;     // 75.5 MB
  bf16_t* Qf    = (bf16_t*)wp;  wp += (size_t)64 * 1024 * 128 * 2; // 16.8 MB
  bf16_t* Kf    = (bf16_t*)wp;  wp += (size_t)64 * 1024 * 128 * 2;
  bf16_t* VfT   = (bf16_t*)wp;  wp += (size_t)64 * 1024 * 128 * 2;
  bf16_t* OT    = C9;                         // first 16.8 MB of C9
  bf16_t* WcatO = C9 + (size_t)16 * 1048576;  // C9+32MB: past OT, m-planes dead
  bf16_t* Yaug  = Qf;

  const dim3 gK3(8, 32, 9);           // 1024/128 x 4096/128 x 9 batches
  const dim3 gGemmO(16, 32);
  const int gPackX = (4096 * 3072 / 8) / 256;   // 6144
  const dim3 gPackW9(512, 9);
  const int gPackWO = (2048 * 2048 / 8) / 256;
  const dim3 gLn(4096, 3);
  const int gFft = 64 * 8;
  const int gAtt = 64 * 8;
  const long c9sb = (long)NN * 9216;

  pack_x3<<<gPackX, 256, 0, stream>>>(xr, xi, Ax3);
  pack_w9<<<gPackW9, 256, 0, stream>>>(Wqr, Wqi, Wkr, Wki, Wvr, Wvi, W9);

  // ---- 3-mult batched QKV projection -> C9 [4096][9216] ----
  gemm_k3<<<gK3, 256, 0, stream>>>(Ax3, W9, C9);
  ln_stats3m<<<gLn, 256, 0, stream>>>(C9, lnst3, bqr, bqi, bkr, bki, bvr, bvi);

  // ---- FFTs (3-mult combine + bias + LN fused on load) ----
  fft_kernel<<<gFft, 512, 0, stream>>>(C9, C9, Qf, Qf + 64,
      c9sb, DHH, 9216, 1,
      16 * NN * 128, NN * 128, 128,
      -1.0f, 0.03125f * 0.125f, 2, 0, lnst3, gq, beq, bqr, bqi);
  fft_kernel<<<gFft, 512, 0, stream>>>(C9 + 3072, C9, Kf, Kf + 64,
      c9sb, DHH, 9216, 1,
      16 * NN * 128, NN * 128, 128,
      -1.0f, 0.03125f, 2, 2, lnst3 + 4096, gk, bek, bkr, bki);
  fft_kernel<<<gFft, 512, 0, stream>>>(C9 + 6144, C9, VfT, VfT + 2048,
      c9sb, DHH, 9216, 1,
      16 * 131072, 131072, 0,
      -1.0f, 0.03125f, 2, 1, lnst3 + 8192, gv, bev, bvr, bvi);

  // ---- O weights into C9 tail (m-planes dead after V FFT) ----
  pack_w<<<gPackWO, 256, 0, stream>>>(Wor, Woi, bor, boi, WcatO, bcatO);

  // ---- flash attention -> OT bf16 [bh][128][1024] ----
  fattn<<<gAtt, 256, 0, stream>>>(Qf, Kf, VfT, OT);

  // ---- inverse FFT: OT (d-major bf16) -> Yaug bf16 [4096][2048] ----
  fft_kernel<<<gFft, 512, 0, stream>>>(OT, OT + (size_t)64 * NN, Yaug, Yaug + 1024,
      (long)16 * 128 * NN, 128 * NN, 1, NN,
      NN * 2048, 64, 2048,
      +1.0f, 0.03125f, 1, 0, nullptr, nullptr, nullptr, nullptr, nullptr);

  // ---- output projection straight into d_out ----
  float* yout = (float*)d_out;
  gemm_bf16<<<gGemmO, 256, 0, stream>>>(Yaug, WcatO, bcatO,
                                        yout, yout + 1024, 2048);
}

// Round 19
// 404.492 us; speedup vs baseline: 1.0457x; 1.0457x over previous
//
#include <hip/hip_runtime.h>
#include <math.h>

#define BB 4
#define NN 1024
#define DIMM 1024
#define HHH 16
#define DHH 64
#define BN 4096            // B*N rows
#define EPS_LN 1e-6f

typedef __bf16 bf16_t;
typedef __bf16 bf16x8 __attribute__((ext_vector_type(8)));
typedef __bf16 bf16x4 __attribute__((ext_vector_type(4)));
typedef float f32x4 __attribute__((ext_vector_type(4)));
typedef float f32x16 __attribute__((ext_vector_type(16)));
#define MFMA16(a, b, c) __builtin_amdgcn_mfma_f32_16x16x32_bf16(a, b, c, 0, 0, 0)
#define MFMA32(a, b, c) __builtin_amdgcn_mfma_f32_32x32x16_bf16(a, b, c, 0, 0, 0)
#define AS1 __attribute__((address_space(1)))
#define AS3 __attribute__((address_space(3)))

__device__ inline unsigned pk2(float a, float b) {
  union { bf16_t h[2]; unsigned u; } c;
  c.h[0] = (bf16_t)a; c.h[1] = (bf16_t)b;
  return c.u;
}
union U16 { uint4 u; bf16x8 v; };

// ============================================================
// pack_x: Axaug[4096][2048] = bf16([xr | xi])
// ============================================================
__global__ __launch_bounds__(256) void pack_x(
    const float* __restrict__ xr, const float* __restrict__ xi,
    bf16_t* __restrict__ out)
{
  int t = blockIdx.x * 256 + threadIdx.x;
  size_t e = (size_t)t * 8;
  int row = (int)(e >> 11), col = (int)(e & 2047);
  const float* src = (col < 1024) ? (xr + (size_t)row * 1024 + col)
                                  : (xi + (size_t)row * 1024 + col - 1024);
  float4 a = *(const float4*)src;
  float4 b = *(const float4*)(src + 4);
  bf16x8 o;
  o[0] = (bf16_t)a.x; o[1] = (bf16_t)a.y; o[2] = (bf16_t)a.z; o[3] = (bf16_t)a.w;
  o[4] = (bf16_t)b.x; o[5] = (bf16_t)b.y; o[6] = (bf16_t)b.z; o[7] = (bf16_t)b.w;
  *(bf16x8*)(out + e) = o;
}

// ============================================================
// pack_w4: all FOUR projections' augmented weights in ONE launch.
// grid (2048, 4); slice p at Wcat4 + p*2048*2048, bcat4 + p*2048.
// rows 0-1023 = [Wr | -Wi], rows 1024-2047 = [Wi | Wr].
// ============================================================
__global__ __launch_bounds__(256) void pack_w4(
    const float* __restrict__ Wqr, const float* __restrict__ Wqi,
    const float* __restrict__ bqr, const float* __restrict__ bqi,
    const float* __restrict__ Wkr, const float* __restrict__ Wki,
    const float* __restrict__ bkr, const float* __restrict__ bki,
    const float* __restrict__ Wvr, const float* __restrict__ Wvi,
    const float* __restrict__ bvr, const float* __restrict__ bvi,
    const float* __restrict__ Wor, const float* __restrict__ Woi,
    const float* __restrict__ bor, const float* __restrict__ boi,
    bf16_t* __restrict__ Wcat4, float* __restrict__ bcat4)
{
  const int p = blockIdx.y;
  const float* Wr; const float* Wi; const float* br; const float* bi;
  if (p == 0)      { Wr = Wqr; Wi = Wqi; br = bqr; bi = bqi; }
  else if (p == 1) { Wr = Wkr; Wi = Wki; br = bkr; bi = bki; }
  else if (p == 2) { Wr = Wvr; Wi = Wvi; br = bvr; bi = bvi; }
  else             { Wr = Wor; Wi = Woi; br = bor; bi = boi; }
  bf16_t* Wcat = Wcat4 + (size_t)p * 2048 * 2048;
  float*  bcat = bcat4 + (size_t)p * 2048;

  int t = blockIdx.x * 256 + threadIdx.x;
  size_t e = (size_t)t * 8;
  int row = (int)(e >> 11), col = (int)(e & 2047);
  const float* src;
  float sgn = 1.f;
  if (row < 1024) {
    if (col < 1024) src = Wr + (size_t)row * 1024 + col;
    else          { src = Wi + (size_t)row * 1024 + col - 1024; sgn = -1.f; }
  } else {
    int r2 = row - 1024;
    if (col < 1024) src = Wi + (size_t)r2 * 1024 + col;
    else            src = Wr + (size_t)r2 * 1024 + col - 1024;
  }
  float4 a = *(const float4*)src;
  float4 b = *(const float4*)(src + 4);
  bf16x8 o;
  o[0] = (bf16_t)(sgn * a.x); o[1] = (bf16_t)(sgn * a.y);
  o[2] = (bf16_t)(sgn * a.z); o[3] = (bf16_t)(sgn * a.w);
  o[4] = (bf16_t)(sgn * b.x); o[5] = (bf16_t)(sgn * b.y);
  o[6] = (bf16_t)(sgn * b.z); o[7] = (bf16_t)(sgn * b.w);
  *(bf16x8*)(Wcat + e) = o;
  if (e < 2048) {
#pragma unroll
    for (int j = 0; j < 8; ++j) {
      int n = (int)e + j;
      bcat[n] = (n < 1024) ? br[n] : bi[n - 1024];
    }
  }
}

// ============================================================
// Fused QKV GEMM (NT), m97 structure — KNOWN-GOOD (161 us, the
// measured 2-phase ceiling; deep-pipeline/3-mult variants were
// null or regressive per R15/R16/R18).
// C6[4096][6144] bf16 = A[4096][2048] @ Wcat[6144][2048]^T + bias.
// ============================================================
__global__ __launch_bounds__(256) void gemm_qkv(
    const bf16_t* __restrict__ A, const bf16_t* __restrict__ Bt,
    const float* __restrict__ bias, bf16_t* __restrict__ C6)
{
  __shared__ bf16_t sA[128 * 64];
  __shared__ bf16_t sB[128 * 64];
  const int tid = threadIdx.x;
  const int w = tid >> 6, l = tid & 63;
  const int lo4 = l & 15, hi = l >> 4;
  const int wr = w >> 1, wc = w & 1;
  const int row0 = blockIdx.y * 128, col0 = blockIdx.x * 128;

  const int srow = (l >> 3);
  const int scol = (l & 7) * 8;
  const bf16_t* gA[4];
  const bf16_t* gB[4];
#pragma unroll
  for (int i = 0; i < 4; ++i) {
    int r = (w * 4 + i) * 8 + srow;
    gA[i] = A  + (size_t)(row0 + r) * 2048 + scol;
    gB[i] = Bt + (size_t)(col0 + r) * 2048 + scol;
  }

  f32x4 acc[4][4] = {};
  for (int k0 = 0; k0 < 2048; k0 += 64) {
    __syncthreads();
#pragma unroll
    for (int i = 0; i < 4; ++i) {
      __builtin_amdgcn_global_load_lds((const AS1 void*)(gA[i] + k0),
                                       (AS3 void*)&sA[(w * 4 + i) * 512], 16, 0, 0);
      __builtin_amdgcn_global_load_lds((const AS1 void*)(gB[i] + k0),
                                       (AS3 void*)&sB[(w * 4 + i) * 512], 16, 0, 0);
    }
    __syncthreads();
#pragma unroll
    for (int kk = 0; kk < 2; ++kk) {
      bf16x8 am[4], bn[4];
#pragma unroll
      for (int i = 0; i < 4; ++i)
        am[i] = *(const bf16x8*)&sA[(wr * 64 + i * 16 + lo4) * 64 + kk * 32 + hi * 8];
#pragma unroll
      for (int j = 0; j < 4; ++j)
        bn[j] = *(const bf16x8*)&sB[(wc * 64 + j * 16 + lo4) * 64 + kk * 32 + hi * 8];
#pragma unroll
      for (int i = 0; i < 4; ++i)
#pragma unroll
        for (int j = 0; j < 4; ++j)
          acc[i][j] = MFMA16(am[i], bn[j], acc[i][j]);
    }
  }
  const int colg0 = col0 + wc * 64;
#pragma unroll
  for (int i = 0; i < 4; ++i) {
#pragma unroll
    for (int j = 0; j < 4; ++j) {
      float bv = bias[colg0 + j * 16 + lo4];
#pragma unroll
      for (int r = 0; r < 4; ++r) {
        int rowg = row0 + wr * 64 + i * 16 + hi * 4 + r;
        C6[(size_t)rowg * 6144 + colg0 + j * 16 + lo4] = (bf16_t)(acc[i][j][r] + bv);
      }
    }
  }
}

// ============================================================
// O-projection GEMM (known-good, fp32 split output).
// ============================================================
__global__ __launch_bounds__(256) void gemm_bf16(
    const bf16_t* __restrict__ A, const bf16_t* __restrict__ Bt,
    const float* __restrict__ bias,
    float* __restrict__ Cr, float* __restrict__ Ci, int ldc)
{
  __shared__ bf16_t sA[128 * 64];
  __shared__ bf16_t sB[128 * 64];
  const int tid = threadIdx.x;
  const int w = tid >> 6, l = tid & 63;
  const int lo4 = l & 15, hi = l >> 4;
  const int wr = w >> 1, wc = w & 1;
  const int row0 = blockIdx.y * 128, col0 = blockIdx.x * 128;

  const int srow = (l >> 3);
  const int scol = (l & 7) * 8;
  const bf16_t* gA[4];
  const bf16_t* gB[4];
#pragma unroll
  for (int i = 0; i < 4; ++i) {
    int r = (w * 4 + i) * 8 + srow;
    gA[i] = A  + (size_t)(row0 + r) * 2048 + scol;
    gB[i] = Bt + (size_t)(col0 + r) * 2048 + scol;
  }

  f32x4 acc[4][4] = {};
  for (int k0 = 0; k0 < 2048; k0 += 64) {
    __syncthreads();
#pragma unroll
    for (int i = 0; i < 4; ++i) {
      __builtin_amdgcn_global_load_lds((const AS1 void*)(gA[i] + k0),
                                       (AS3 void*)&sA[(w * 4 + i) * 512], 16, 0, 0);
      __builtin_amdgcn_global_load_lds((const AS1 void*)(gB[i] + k0),
                                       (AS3 void*)&sB[(w * 4 + i) * 512], 16, 0, 0);
    }
    __syncthreads();
#pragma unroll
    for (int kk = 0; kk < 2; ++kk) {
      bf16x8 am[4], bn[4];
#pragma unroll
      for (int i = 0; i < 4; ++i)
        am[i] = *(const bf16x8*)&sA[(wr * 64 + i * 16 + lo4) * 64 + kk * 32 + hi * 8];
#pragma unroll
      for (int j = 0; j < 4; ++j)
        bn[j] = *(const bf16x8*)&sB[(wc * 64 + j * 16 + lo4) * 64 + kk * 32 + hi * 8];
#pragma unroll
      for (int i = 0; i < 4; ++i)
#pragma unroll
        for (int j = 0; j < 4; ++j)
          acc[i][j] = MFMA16(am[i], bn[j], acc[i][j]);
    }
  }
  const int colg0 = col0 + wc * 64;
  float* Cp = (colg0 < 1024) ? Cr : Ci;
  const int cb = colg0 & 1023;
#pragma unroll
  for (int i = 0; i < 4; ++i) {
#pragma unroll
    for (int j = 0; j < 4; ++j) {
      float bv = bias[colg0 + j * 16 + lo4];
#pragma unroll
      for (int r = 0; r < 4; ++r) {
        int rowg = row0 + wr * 64 + i * 16 + hi * 4 + r;
        Cp[(size_t)rowg * ldc + cb + j * 16 + lo4] = acc[i][j][r] + bv;
      }
    }
  }
}

// ============================================================
// LN row stats over bf16 C6.
// ============================================================
__global__ __launch_bounds__(256) void ln_stats3(
    const bf16_t* __restrict__ C6, float2* __restrict__ st)
{
  __shared__ float red[8];
  const int row = blockIdx.x;
  const int p = blockIdx.y;
  const int tid = threadIdx.x;
  const bf16_t* pr = C6 + (size_t)row * 6144 + p * 2048;
  const bf16_t* pi = pr + 1024;
  bf16x4 vr = *(const bf16x4*)(pr + tid * 4);
  bf16x4 vi = *(const bf16x4*)(pi + tid * 4);
  float s = 0.f, s2 = 0.f;
#pragma unroll
  for (int t = 0; t < 4; ++t) {
    float a = (float)vr[t], b = (float)vi[t];
    float mg = sqrtf(a * a + b * b);
    s += mg; s2 += mg * mg;
  }
#pragma unroll
  for (int o = 32; o; o >>= 1) { s += __shfl_down(s, o); s2 += __shfl_down(s2, o); }
  if ((tid & 63) == 0) { red[tid >> 6] = s; red[4 + (tid >> 6)] = s2; }
  __syncthreads();
  if (tid == 0) {
    float S = red[0] + red[1] + red[2] + red[3];
    float S2 = red[4] + red[5] + red[6] + red[7];
    float mean = S * (1.f / DIMM);
    float var = S2 * (1.f / DIMM) - mean * mean;
    st[(size_t)p * 4096 + row] = make_float2(mean, rsqrtf(var + EPS_LN));
  }
}

// ============================================================
// 1024-pt RADIX-4 DIF FFT v3 — bf16 in/out.
// ============================================================
#define LIDX(d_, c_) (((d_) << 10) + ((c_) ^ (((c_) >> 5) & 31) ^ (((d_) & 7) << 2)))

__global__ __launch_bounds__(512) void fft_kernel(
    const bf16_t* __restrict__ inR, const bf16_t* __restrict__ inI,
    bf16_t* __restrict__ outR, bf16_t* __restrict__ outI,
    int in_sb, int in_sh, int in_sn, int in_sd,
    int out_sb, int out_sh, int out_sn,
    float sign, float oscale, int imode, int omode,
    const float2* __restrict__ stats,
    const float* __restrict__ gamma, const float* __restrict__ beta)
{
  __shared__ float lr[8 * 1024], li[8 * 1024];
  __shared__ float2 tw[1024];
  const int tid = threadIdx.x;
  const int dc = blockIdx.x & 7;
  const int bh = blockIdx.x >> 3;
  const int b = bh >> 4, h = bh & 15;
  const bf16_t* bR = inR + (size_t)b * in_sb + (size_t)h * in_sh;
  const bf16_t* bI = inI + (size_t)b * in_sb + (size_t)h * in_sh;
#pragma unroll
  for (int t = tid; t < 1024; t += 512) {
    float ang = sign * 3.14159265358979323846f * (float)t * (1.f / 512.f);
    float sn, cs;
    __sincosf(ang, &sn, &cs);
    tw[t] = make_float2(cs, sn);
  }
  if (imode == 0) {
    float gg[8], bb[8];
    if (stats) {
#pragma unroll
      for (int ds = 0; ds < 8; ++ds) {
        gg[ds] = gamma[h * DHH + dc * 8 + ds];
        bb[ds] = beta[h * DHH + dc * 8 + ds];
      }
    }
#pragma unroll
    for (int rep = 0; rep < 2; ++rep) {
      int n = tid + rep * 512;
      bf16x8 r8 = *(const bf16x8*)(bR + (size_t)n * in_sn + dc * 8);
      bf16x8 i8 = *(const bf16x8*)(bI + (size_t)n * in_sn + dc * 8);
      float ur[8], ui[8];
#pragma unroll
      for (int ds = 0; ds < 8; ++ds) { ur[ds] = (float)r8[ds]; ui[ds] = (float)i8[ds]; }
      if (stats) {
        float2 stv = stats[b * NN + n];
#pragma unroll
        for (int ds = 0; ds < 8; ++ds) {
          float a = ur[ds], c2 = ui[ds];
          float mag = sqrtf(a * a + c2 * c2);
          float nm = (mag - stv.x) * stv.y * gg[ds] + bb[ds];
          if (mag > 0.f) { float sc = nm / mag; ur[ds] = a * sc; ui[ds] = c2 * sc; }
          else           { ur[ds] = nm; ui[ds] = 0.f; }
        }
      }
#pragma unroll
      for (int ds = 0; ds < 8; ++ds) {
        int ax = LIDX(ds, n);
        lr[ax] = ur[ds];
        li[ax] = ui[ds];
      }
    }
  } else {
    const int ds = tid & 7, nb = tid >> 3;
    const bf16_t* pR = bR + (size_t)(dc * 8 + ds) * in_sd + nb * 16;
    const bf16_t* pI = bI + (size_t)(dc * 8 + ds) * in_sd + nb * 16;
    bf16x8 a0 = *(const bf16x8*)pR, a1 = *(const bf16x8*)(pR + 8);
    bf16x8 b0 = *(const bf16x8*)pI, b1 = *(const bf16x8*)(pI + 8);
#pragma unroll
    for (int k = 0; k < 8; ++k) {
      int c = nb * 16 + k;
      lr[LIDX(ds, c)] = (float)a0[k];       li[LIDX(ds, c)] = (float)b0[k];
      lr[LIDX(ds, c + 8)] = (float)a1[k];   li[LIDX(ds, c + 8)] = (float)b1[k];
    }
  }
  __syncthreads();
  const int dsub = tid & 7;
  const int jb = tid >> 3;
  int lq2 = 8;
  for (int st = 0; st < 5; ++st) {
    const int qtr = 1 << lq2;
    const int tmul = 1 << (2 * st);
    for (int jt = 0; jt < 4; ++jt) {
      int j = jb + jt * 64;
      int o = j & (qtr - 1);
      int i0 = ((j >> lq2) << (lq2 + 2)) + o;
      int a0 = LIDX(dsub, i0);
      int a1 = LIDX(dsub, i0 + qtr);
      int a2 = LIDX(dsub, i0 + 2 * qtr);
      int a3 = LIDX(dsub, i0 + 3 * qtr);
      float x0r = lr[a0], x0i = li[a0];
      float x1r = lr[a1], x1i = li[a1];
      float x2r = lr[a2], x2i = li[a2];
      float x3r = lr[a3], x3i = li[a3];
      float ar = x0r + x2r, ai2 = x0i + x2i;
      float br = x0r - x2r, bi  = x0i - x2i;
      float cr = x1r + x3r, ci  = x1i + x3i;
      float dr = x1r - x3r, di  = x1i - x3i;
      float2 t1 = tw[o * tmul];
      float2 t2 = tw[2 * o * tmul];
      float2 t3 = tw[3 * o * tmul];
      lr[a0] = ar + cr;  li[a0] = ai2 + ci;
      float u1r = br - sign * di, u1i = bi + sign * dr;
      lr[a1] = u1r * t1.x - u1i * t1.y;  li[a1] = u1r * t1.y + u1i * t1.x;
      float u2r = ar - cr, u2i = ai2 - ci;
      lr[a2] = u2r * t2.x - u2i * t2.y;  li[a2] = u2r * t2.y + u2i * t2.x;
      float u3r = br + sign * di, u3i = bi - sign * dr;
      lr[a3] = u3r * t3.x - u3i * t3.y;  li[a3] = u3r * t3.y + u3i * t3.x;
    }
    __syncthreads();
    lq2 -= 2;
  }
  bf16_t* oRb = outR + (size_t)b * out_sb + (size_t)h * out_sh;
  bf16_t* oIb = outI + (size_t)b * out_sb + (size_t)h * out_sh;
#pragma unroll
  for (int rep = 0; rep < 2; ++rep) {
    int n = tid + rep * 512;
    int rv2 = __brev((unsigned)n) >> 22;
    int p = ((rv2 & 0x155) << 1) | ((rv2 >> 1) & 0x155);
    float fr[8], fi[8];
#pragma unroll
    for (int ds = 0; ds < 8; ++ds) {
      fr[ds] = lr[LIDX(ds, p)] * oscale;
      fi[ds] = li[LIDX(ds, p)] * oscale;
    }
    if (omode == 1) {
      size_t tb = (size_t)(n >> 5) * 4096;
#pragma unroll
      for (int ds = 0; ds < 8; ++ds) {
        int dch = dc * 8 + ds;
        size_t ga = tb + (size_t)dch * 32 + ((n & 31) ^ (((dch >> 1) & 3) << 3));
        oRb[ga] = (bf16_t)fr[ds];
        oIb[ga] = (bf16_t)fi[ds];
      }
    } else {
      int cb = dc * 8;
      if (omode == 2) cb = (dc ^ (n & 7)) * 8;
      bf16x8 v0, w0;
#pragma unroll
      for (int k = 0; k < 8; ++k) {
        v0[k] = (bf16_t)fr[k];
        w0[k] = (bf16_t)fi[k];
      }
      size_t gb = (size_t)n * out_sn + cb;
      *(bf16x8*)(oRb + gb) = v0;
      *(bf16x8*)(oIb + gb) = w0;
    }
  }
}

// ============================================================
// Flash attention v7 (known-good control).
// ============================================================
__global__ __launch_bounds__(256, 2) void fattn(
    const bf16_t* __restrict__ Qf, const bf16_t* __restrict__ Kfs,
    const bf16_t* __restrict__ Vfs, bf16_t* __restrict__ OT)
{
  __shared__ bf16_t K3[3][4096];
  __shared__ bf16_t V3[3][4096];
  const int tid = threadIdx.x;
  const int w = tid >> 6, l = tid & 63;
  const int lq = l & 31;
  const int h = l >> 5;
  const int i = blockIdx.x;
  const int j = i >> 3;
  const int bh = (i & 7) * 8 + (j >> 3);
  const int q0 = (j & 7) * 128 + w * 32;

  bf16x8 bq[8];
  const bf16_t* qp = Qf + ((size_t)bh * NN + q0 + lq) * 128 + h * 8;
#pragma unroll
  for (int kk = 0; kk < 8; ++kk) bq[kk] = *(const bf16x8*)(qp + kk * 16);

  f32x16 o[4] = {};
  float m = -3e38f, ln = 0.f;

  const bf16_t* kg = Kfs + (size_t)bh * 131072 + w * 1024 + l * 8;
  const bf16_t* vg = Vfs + (size_t)bh * 131072 + w * 1024 + l * 8;
  const int kswz = (lq & 7) << 3;
  const int vswz = ((lq >> 1) & 3) << 3;

#pragma unroll
  for (int tt = 0; tt < 2; ++tt) {
    const bf16_t* kt = kg + (size_t)tt * 4096;
    const bf16_t* vt = vg + (size_t)tt * 4096;
#pragma unroll
    for (int ii = 0; ii < 2; ++ii) {
      __builtin_amdgcn_global_load_lds((const AS1 void*)(kt + ii * 512),
                                       (AS3 void*)&K3[tt][w * 1024 + ii * 512], 16, 0, 0);
      __builtin_amdgcn_global_load_lds((const AS1 void*)(vt + ii * 512),
                                       (AS3 void*)&V3[tt][w * 1024 + ii * 512], 16, 0, 0);
    }
  }
  asm volatile("s_waitcnt vmcnt(4)" ::: "memory");
  __builtin_amdgcn_s_barrier();
  __builtin_amdgcn_sched_barrier(0);

  int cur = 0;
  for (int t = 0; t < 32; ++t) {
    if (t < 30) {
      int nb = cur + 2; if (nb >= 3) nb -= 3;
      const bf16_t* kt = kg + (size_t)(t + 2) * 4096;
      const bf16_t* vt = vg + (size_t)(t + 2) * 4096;
#pragma unroll
      for (int ii = 0; ii < 2; ++ii) {
        __builtin_amdgcn_global_load_lds((const AS1 void*)(kt + ii * 512),
                                         (AS3 void*)&K3[nb][w * 1024 + ii * 512], 16, 0, 0);
        __builtin_amdgcn_global_load_lds((const AS1 void*)(vt + ii * 512),
                                         (AS3 void*)&V3[nb][w * 1024 + ii * 512], 16, 0, 0);
      }
    }

    f32x16 s = {};
#pragma unroll
    for (int kk = 0; kk < 8; ++kk) {
      bf16x8 ak = *(const bf16x8*)&K3[cur][lq * 128 + ((kk * 16 + h * 8) ^ kswz)];
      s = MFMA32(ak, bq[kk], s);
    }

    float pmax = s[0];
#pragma unroll
    for (int r = 1; r < 16; ++r) pmax = fmaxf(pmax, s[r]);
    pmax = fmaxf(pmax, __shfl_xor(pmax, 32));
    if (!__all(pmax - m <= 8.f)) {
      float mnew = fmaxf(m, pmax);
      float alpha = __expf(m - mnew);
      m = mnew;
      ln *= alpha;
#pragma unroll
      for (int db = 0; db < 4; ++db)
#pragma unroll
        for (int r = 0; r < 16; ++r) o[db][r] *= alpha;
    }
    float pf[16];
    float rs = 0.f;
#pragma unroll
    for (int r = 0; r < 16; ++r) { pf[r] = __expf(s[r] - m); rs += pf[r]; }
    rs += __shfl_xor(rs, 32);
    ln += rs;

    unsigned pw[8];
#pragma unroll
    for (int ii = 0; ii < 8; ++ii) pw[ii] = pk2(pf[2 * ii], pf[2 * ii + 1]);
    unsigned r0 = (unsigned)__shfl_xor((int)(h ? pw[0] : pw[2]), 32);
    unsigned r1 = (unsigned)__shfl_xor((int)(h ? pw[1] : pw[3]), 32);
    unsigned r2 = (unsigned)__shfl_xor((int)(h ? pw[4] : pw[6]), 32);
    unsigned r3 = (unsigned)__shfl_xor((int)(h ? pw[5] : pw[7]), 32);
    U16 bp0, bp1;
    bp0.u.x = h ? r0 : pw[0];  bp0.u.y = h ? r1 : pw[1];
    bp0.u.z = h ? pw[2] : r0;  bp0.u.w = h ? pw[3] : r1;
    bp1.u.x = h ? r2 : pw[4];  bp1.u.y = h ? r3 : pw[5];
    bp1.u.z = h ? pw[6] : r2;  bp1.u.w = h ? pw[7] : r3;

#pragma unroll
    for (int db = 0; db < 4; ++db) {
      int r = db * 32 + lq;
      bf16x8 av0 = *(const bf16x8*)&V3[cur][r * 32 + ((h * 8) ^ vswz)];
      bf16x8 av1 = *(const bf16x8*)&V3[cur][r * 32 + ((16 + h * 8) ^ vswz)];
      o[db] = MFMA32(av0, bp0.v, o[db]);
      o[db] = MFMA32(av1, bp1.v, o[db]);
    }

    if (t < 31) {
      if (t < 30) asm volatile("s_waitcnt vmcnt(4)" ::: "memory");
      else        asm volatile("s_waitcnt vmcnt(0)" ::: "memory");
      __builtin_amdgcn_s_barrier();
      __builtin_amdgcn_sched_barrier(0);
    }
    cur = (cur == 2) ? 0 : cur + 1;
  }

  float inv = 1.f / ln;
  const size_t otb = (size_t)bh * 128 * NN + q0 + lq;
#pragma unroll
  for (int db = 0; db < 4; ++db)
#pragma unroll
    for (int r = 0; r < 16; ++r) {
      int dl = (r & 3) + 8 * (r >> 2) + 4 * h;
      OT[otb + (size_t)(db * 32 + dl) * NN] = (bf16_t)(o[db][r] * inv);
    }
}

// ============================================================
// Host-side orchestration
// ============================================================
extern "C" void kernel_launch(void* const* d_in, const int* in_sizes, int n_in,
                              void* d_out, int out_size, void* d_ws, size_t ws_size,
                              hipStream_t stream) {
  const float* xr   = (const float*)d_in[0];
  const float* xi   = (const float*)d_in[1];
  const float* Wqr  = (const float*)d_in[2];
  const float* Wqi  = (const float*)d_in[3];
  const float* bqr  = (const float*)d_in[4];
  const float* bqi  = (const float*)d_in[5];
  const float* Wkr  = (const float*)d_in[6];
  const float* Wki  = (const float*)d_in[7];
  const float* bkr  = (const float*)d_in[8];
  const float* bki  = (const float*)d_in[9];
  const float* Wvr  = (const float*)d_in[10];
  const float* Wvi  = (const float*)d_in[11];
  const float* bvr  = (const float*)d_in[12];
  const float* bvi  = (const float*)d_in[13];
  const float* Wor  = (const float*)d_in[14];
  const float* Woi  = (const float*)d_in[15];
  const float* bor  = (const float*)d_in[16];
  const float* boi  = (const float*)d_in[17];
  const float* gq   = (const float*)d_in[18];
  const float* beq  = (const float*)d_in[19];
  const float* gk   = (const float*)d_in[20];
  const float* bek  = (const float*)d_in[21];
  const float* gv   = (const float*)d_in[22];
  const float* bev  = (const float*)d_in[23];

  char* wp = (char*)d_ws;
  bf16_t* Axaug = (bf16_t*)wp;  wp += (size_t)4096 * 2048 * 2;     // 16.8 MB
  bf16_t* Wcat4 = (bf16_t*)wp;  wp += (size_t)8192 * 2048 * 2;     // 33.6 MB
  float*  bcat4 = (float*)wp;   wp += (size_t)8192 * 4;
  float2* lnst3 = (float2*)wp;  wp += (size_t)3 * 4096 * 8;
  bf16_t* C6    = (bf16_t*)wp;  wp += (size_t)4096 * 6144 * 2;     // 50.3 MB
  bf16_t* Qf    = (bf16_t*)wp;  wp += (size_t)64 * 1024 * 128 * 2;
  bf16_t* Kf    = (bf16_t*)wp;  wp += (size_t)64 * 1024 * 128 * 2;
  bf16_t* VfT   = (bf16_t*)wp;  wp += (size_t)64 * 1024 * 128 * 2;
  bf16_t* OT    = C6;    // attn output aliases C6 (dead after V's FFT)
  bf16_t* Yaug  = Qf;    // iFFT output aliases Qf (dead after fattn)

  const dim3 gQKV(48, 32);            // 6144/128 x 4096/128 = 1536 blocks
  const dim3 gGemmO(16, 32);
  const int gPackX = (4096 * 2048 / 8) / 256;
  const dim3 gPackW(2048, 4);
  const dim3 gLn(4096, 3);
  const int gFft = 64 * 8;
  const int gAtt = 64 * 8;

  pack_x<<<gPackX, 256, 0, stream>>>(xr, xi, Axaug);
  pack_w4<<<gPackW, 256, 0, stream>>>(Wqr, Wqi, bqr, bqi,
                                      Wkr, Wki, bkr, bki,
                                      Wvr, Wvi, bvr, bvi,
                                      Wor, Woi, bor, boi,
                                      Wcat4, bcat4);

  // ---- fused QKV projection -> C6 bf16 [4096][6144] ----
  gemm_qkv<<<gQKV, 256, 0, stream>>>(Axaug, Wcat4, bcat4, C6);
  ln_stats3<<<gLn, 256, 0, stream>>>(C6, lnst3);

  // ---- FFTs (LN fused on load); Q carries the 1/8 attention scale ----
  fft_kernel<<<gFft, 512, 0, stream>>>(C6, C6 + 1024, Qf, Qf + 64,
      NN * 6144, DHH, 6144, 1,
      16 * NN * 128, NN * 128, 128,
      -1.0f, 0.03125f * 0.125f, 0, 0, lnst3, gq, beq);
  fft_kernel<<<gFft, 512, 0, stream>>>(C6 + 2048, C6 + 3072, Kf, Kf + 64,
      NN * 6144, DHH, 6144, 1,
      16 * NN * 128, NN * 128, 128,
      -1.0f, 0.03125f, 0, 2, lnst3 + 4096, gk, bek);
  fft_kernel<<<gFft, 512, 0, stream>>>(C6 + 4096, C6 + 5120, VfT, VfT + 2048,
      NN * 6144, DHH, 6144, 1,
      16 * 131072, 131072, 0,
      -1.0f, 0.03125f, 0, 1, lnst3 + 8192, gv, bev);

  // ---- flash attention -> OT bf16 [bh][128][1024] ----
  fattn<<<gAtt, 256, 0, stream>>>(Qf, Kf, VfT, OT);

  // ---- inverse FFT: OT (d-major bf16) -> Yaug bf16 [4096][2048] ----
  fft_kernel<<<gFft, 512, 0, stream>>>(OT, OT + (size_t)64 * NN, Yaug, Yaug + 1024,
      16 * 128 * NN, 128 * NN, 1, NN,
      NN * 2048, 64, 2048,
      +1.0f, 0.03125f, 1, 0, nullptr, nullptr, nullptr);

  // ---- output projection straight into d_out (slice 3 of Wcat4) ----
  float* yout = (float*)d_out;
  gemm_bf16<<<gGemmO, 256, 0, stream>>>(Yaug,
      Wcat4 + (size_t)3 * 2048 * 2048, bcat4 + 3 * 2048,
      yout, yout + 1024, 2048);
}

// Round 20
// 402.076 us; speedup vs baseline: 1.0520x; 1.0060x over previous
//
#include <hip/hip_runtime.h>
#include <math.h>

#define BB 4
#define NN 1024
#define DIMM 1024
#define HHH 16
#define DHH 64
#define BN 4096            // B*N rows
#define EPS_LN 1e-6f

typedef __bf16 bf16_t;
typedef __bf16 bf16x8 __attribute__((ext_vector_type(8)));
typedef __bf16 bf16x4 __attribute__((ext_vector_type(4)));
typedef float f32x4 __attribute__((ext_vector_type(4)));
typedef float f32x16 __attribute__((ext_vector_type(16)));
#define MFMA16(a, b, c) __builtin_amdgcn_mfma_f32_16x16x32_bf16(a, b, c, 0, 0, 0)
#define MFMA32(a, b, c) __builtin_amdgcn_mfma_f32_32x32x16_bf16(a, b, c, 0, 0, 0)
#define AS1 __attribute__((address_space(1)))
#define AS3 __attribute__((address_space(3)))

__device__ inline unsigned pk2(float a, float b) {
  union { bf16_t h[2]; unsigned u; } c;
  c.h[0] = (bf16_t)a; c.h[1] = (bf16_t)b;
  return c.u;
}
union U16 { uint4 u; bf16x8 v; };

// ============================================================
// pack_x: Axaug[4096][2048] = bf16([xr | xi])
// ============================================================
__global__ __launch_bounds__(256) void pack_x(
    const float* __restrict__ xr, const float* __restrict__ xi,
    bf16_t* __restrict__ out)
{
  int t = blockIdx.x * 256 + threadIdx.x;
  size_t e = (size_t)t * 8;
  int row = (int)(e >> 11), col = (int)(e & 2047);
  const float* src = (col < 1024) ? (xr + (size_t)row * 1024 + col)
                                  : (xi + (size_t)row * 1024 + col - 1024);
  float4 a = *(const float4*)src;
  float4 b = *(const float4*)(src + 4);
  bf16x8 o;
  o[0] = (bf16_t)a.x; o[1] = (bf16_t)a.y; o[2] = (bf16_t)a.z; o[3] = (bf16_t)a.w;
  o[4] = (bf16_t)b.x; o[5] = (bf16_t)b.y; o[6] = (bf16_t)b.z; o[7] = (bf16_t)b.w;
  *(bf16x8*)(out + e) = o;
}

// ============================================================
// pack_w4: all FOUR projections' augmented weights in ONE launch.
// ============================================================
__global__ __launch_bounds__(256) void pack_w4(
    const float* __restrict__ Wqr, const float* __restrict__ Wqi,
    const float* __restrict__ bqr, const float* __restrict__ bqi,
    const float* __restrict__ Wkr, const float* __restrict__ Wki,
    const float* __restrict__ bkr, const float* __restrict__ bki,
    const float* __restrict__ Wvr, const float* __restrict__ Wvi,
    const float* __restrict__ bvr, const float* __restrict__ bvi,
    const float* __restrict__ Wor, const float* __restrict__ Woi,
    const float* __restrict__ bor, const float* __restrict__ boi,
    bf16_t* __restrict__ Wcat4, float* __restrict__ bcat4)
{
  const int p = blockIdx.y;
  const float* Wr; const float* Wi; const float* br; const float* bi;
  if (p == 0)      { Wr = Wqr; Wi = Wqi; br = bqr; bi = bqi; }
  else if (p == 1) { Wr = Wkr; Wi = Wki; br = bkr; bi = bki; }
  else if (p == 2) { Wr = Wvr; Wi = Wvi; br = bvr; bi = bvi; }
  else             { Wr = Wor; Wi = Woi; br = bor; bi = boi; }
  bf16_t* Wcat = Wcat4 + (size_t)p * 2048 * 2048;
  float*  bcat = bcat4 + (size_t)p * 2048;

  int t = blockIdx.x * 256 + threadIdx.x;
  size_t e = (size_t)t * 8;
  int row = (int)(e >> 11), col = (int)(e & 2047);
  const float* src;
  float sgn = 1.f;
  if (row < 1024) {
    if (col < 1024) src = Wr + (size_t)row * 1024 + col;
    else          { src = Wi + (size_t)row * 1024 + col - 1024; sgn = -1.f; }
  } else {
    int r2 = row - 1024;
    if (col < 1024) src = Wi + (size_t)r2 * 1024 + col;
    else            src = Wr + (size_t)r2 * 1024 + col - 1024;
  }
  float4 a = *(const float4*)src;
  float4 b = *(const float4*)(src + 4);
  bf16x8 o;
  o[0] = (bf16_t)(sgn * a.x); o[1] = (bf16_t)(sgn * a.y);
  o[2] = (bf16_t)(sgn * a.z); o[3] = (bf16_t)(sgn * a.w);
  o[4] = (bf16_t)(sgn * b.x); o[5] = (bf16_t)(sgn * b.y);
  o[6] = (bf16_t)(sgn * b.z); o[7] = (bf16_t)(sgn * b.w);
  *(bf16x8*)(Wcat + e) = o;
  if (e < 2048) {
#pragma unroll
    for (int j = 0; j < 8; ++j) {
      int n = (int)e + j;
      bcat[n] = (n < 1024) ? br[n] : bi[n - 1024];
    }
  }
}

// ============================================================
// Fused QKV GEMM (NT), m97 2-phase known-good + T1 XCD swizzle:
// 1536 blocks, each XCD owns bx in [6x, 6x+6) x all by -> its W
// working set (3.1 MB) fits the 4 MB XCD L2. Bijective (1536%8==0).
// ============================================================
__global__ __launch_bounds__(256) void gemm_qkv(
    const bf16_t* __restrict__ A, const bf16_t* __restrict__ Bt,
    const float* __restrict__ bias, bf16_t* __restrict__ C6)
{
  __shared__ bf16_t sA[128 * 64];
  __shared__ bf16_t sB[128 * 64];
  const int tid = threadIdx.x;
  const int w = tid >> 6, l = tid & 63;
  const int lo4 = l & 15, hi = l >> 4;
  const int wr = w >> 1, wc = w & 1;
  // XCD-locality swizzle (T1)
  const int fid = blockIdx.y * 48 + blockIdx.x;
  const int xcd = fid & 7;
  const int rr2 = fid >> 3;                 // 0..191
  const int bx = xcd * 6 + (rr2 >> 5);      // 0..47
  const int by = rr2 & 31;                  // 0..31
  const int row0 = by * 128, col0 = bx * 128;

  const int srow = (l >> 3);
  const int scol = (l & 7) * 8;
  const bf16_t* gA[4];
  const bf16_t* gB[4];
#pragma unroll
  for (int i = 0; i < 4; ++i) {
    int r = (w * 4 + i) * 8 + srow;
    gA[i] = A  + (size_t)(row0 + r) * 2048 + scol;
    gB[i] = Bt + (size_t)(col0 + r) * 2048 + scol;
  }

  f32x4 acc[4][4] = {};
  for (int k0 = 0; k0 < 2048; k0 += 64) {
    __syncthreads();
#pragma unroll
    for (int i = 0; i < 4; ++i) {
      __builtin_amdgcn_global_load_lds((const AS1 void*)(gA[i] + k0),
                                       (AS3 void*)&sA[(w * 4 + i) * 512], 16, 0, 0);
      __builtin_amdgcn_global_load_lds((const AS1 void*)(gB[i] + k0),
                                       (AS3 void*)&sB[(w * 4 + i) * 512], 16, 0, 0);
    }
    __syncthreads();
#pragma unroll
    for (int kk = 0; kk < 2; ++kk) {
      bf16x8 am[4], bn[4];
#pragma unroll
      for (int i = 0; i < 4; ++i)
        am[i] = *(const bf16x8*)&sA[(wr * 64 + i * 16 + lo4) * 64 + kk * 32 + hi * 8];
#pragma unroll
      for (int j = 0; j < 4; ++j)
        bn[j] = *(const bf16x8*)&sB[(wc * 64 + j * 16 + lo4) * 64 + kk * 32 + hi * 8];
#pragma unroll
      for (int i = 0; i < 4; ++i)
#pragma unroll
        for (int j = 0; j < 4; ++j)
          acc[i][j] = MFMA16(am[i], bn[j], acc[i][j]);
    }
  }
  const int colg0 = col0 + wc * 64;
#pragma unroll
  for (int i = 0; i < 4; ++i) {
#pragma unroll
    for (int j = 0; j < 4; ++j) {
      float bv = bias[colg0 + j * 16 + lo4];
#pragma unroll
      for (int r = 0; r < 4; ++r) {
        int rowg = row0 + wr * 64 + i * 16 + hi * 4 + r;
        C6[(size_t)rowg * 6144 + colg0 + j * 16 + lo4] = (bf16_t)(acc[i][j][r] + bv);
      }
    }
  }
}

// ============================================================
// O-projection GEMM (known-good + T1 swizzle; 512 blocks, 512%8==0).
// ============================================================
__global__ __launch_bounds__(256) void gemm_bf16(
    const bf16_t* __restrict__ A, const bf16_t* __restrict__ Bt,
    const float* __restrict__ bias,
    float* __restrict__ Cr, float* __restrict__ Ci, int ldc)
{
  __shared__ bf16_t sA[128 * 64];
  __shared__ bf16_t sB[128 * 64];
  const int tid = threadIdx.x;
  const int w = tid >> 6, l = tid & 63;
  const int lo4 = l & 15, hi = l >> 4;
  const int wr = w >> 1, wc = w & 1;
  const int fid = blockIdx.y * 16 + blockIdx.x;
  const int xcd = fid & 7;
  const int rr2 = fid >> 3;                 // 0..63
  const int bx = xcd * 2 + (rr2 >> 5);      // 0..15
  const int by = rr2 & 31;                  // 0..31
  const int row0 = by * 128, col0 = bx * 128;

  const int srow = (l >> 3);
  const int scol = (l & 7) * 8;
  const bf16_t* gA[4];
  const bf16_t* gB[4];
#pragma unroll
  for (int i = 0; i < 4; ++i) {
    int r = (w * 4 + i) * 8 + srow;
    gA[i] = A  + (size_t)(row0 + r) * 2048 + scol;
    gB[i] = Bt + (size_t)(col0 + r) * 2048 + scol;
  }

  f32x4 acc[4][4] = {};
  for (int k0 = 0; k0 < 2048; k0 += 64) {
    __syncthreads();
#pragma unroll
    for (int i = 0; i < 4; ++i) {
      __builtin_amdgcn_global_load_lds((const AS1 void*)(gA[i] + k0),
                                       (AS3 void*)&sA[(w * 4 + i) * 512], 16, 0, 0);
      __builtin_amdgcn_global_load_lds((const AS1 void*)(gB[i] + k0),
                                       (AS3 void*)&sB[(w * 4 + i) * 512], 16, 0, 0);
    }
    __syncthreads();
#pragma unroll
    for (int kk = 0; kk < 2; ++kk) {
      bf16x8 am[4], bn[4];
#pragma unroll
      for (int i = 0; i < 4; ++i)
        am[i] = *(const bf16x8*)&sA[(wr * 64 + i * 16 + lo4) * 64 + kk * 32 + hi * 8];
#pragma unroll
      for (int j = 0; j < 4; ++j)
        bn[j] = *(const bf16x8*)&sB[(wc * 64 + j * 16 + lo4) * 64 + kk * 32 + hi * 8];
#pragma unroll
      for (int i = 0; i < 4; ++i)
#pragma unroll
        for (int j = 0; j < 4; ++j)
          acc[i][j] = MFMA16(am[i], bn[j], acc[i][j]);
    }
  }
  const int colg0 = col0 + wc * 64;
  float* Cp = (colg0 < 1024) ? Cr : Ci;
  const int cb = colg0 & 1023;
#pragma unroll
  for (int i = 0; i < 4; ++i) {
#pragma unroll
    for (int j = 0; j < 4; ++j) {
      float bv = bias[colg0 + j * 16 + lo4];
#pragma unroll
      for (int r = 0; r < 4; ++r) {
        int rowg = row0 + wr * 64 + i * 16 + hi * 4 + r;
        Cp[(size_t)rowg * ldc + cb + j * 16 + lo4] = acc[i][j][r] + bv;
      }
    }
  }
}

// ============================================================
// LN row stats over bf16 C6.
// ============================================================
__global__ __launch_bounds__(256) void ln_stats3(
    const bf16_t* __restrict__ C6, float2* __restrict__ st)
{
  __shared__ float red[8];
  const int row = blockIdx.x;
  const int p = blockIdx.y;
  const int tid = threadIdx.x;
  const bf16_t* pr = C6 + (size_t)row * 6144 + p * 2048;
  const bf16_t* pi = pr + 1024;
  bf16x4 vr = *(const bf16x4*)(pr + tid * 4);
  bf16x4 vi = *(const bf16x4*)(pi + tid * 4);
  float s = 0.f, s2 = 0.f;
#pragma unroll
  for (int t = 0; t < 4; ++t) {
    float a = (float)vr[t], b = (float)vi[t];
    float mg = sqrtf(a * a + b * b);
    s += mg; s2 += mg * mg;
  }
#pragma unroll
  for (int o = 32; o; o >>= 1) { s += __shfl_down(s, o); s2 += __shfl_down(s2, o); }
  if ((tid & 63) == 0) { red[tid >> 6] = s; red[4 + (tid >> 6)] = s2; }
  __syncthreads();
  if (tid == 0) {
    float S = red[0] + red[1] + red[2] + red[3];
    float S2 = red[4] + red[5] + red[6] + red[7];
    float mean = S * (1.f / DIMM);
    float var = S2 * (1.f / DIMM) - mean * mean;
    st[(size_t)p * 4096 + row] = make_float2(mean, rsqrtf(var + EPS_LN));
  }
}

#define LIDX(d_, c_) (((d_) << 10) + ((c_) ^ (((c_) >> 5) & 31) ^ (((d_) & 7) << 2)))

// ============================================================
// fft_qkv: all THREE forward FFTs in ONE launch, grid (512, 3).
// y=0: Q (omode 0, scale 1/32*1/8), y=1: K (omode 2), y=2: V (omode 1).
// Bodies identical to fft_kernel imode-0 path; out_sb/out_sh equal
// across the three (2097152 / 131072).
// ============================================================
__global__ __launch_bounds__(512) void fft_qkv(
    const bf16_t* __restrict__ C6,
    bf16_t* __restrict__ Qf, bf16_t* __restrict__ Kf, bf16_t* __restrict__ VfT,
    const float2* __restrict__ lnst3,
    const float* __restrict__ gq, const float* __restrict__ beq,
    const float* __restrict__ gk, const float* __restrict__ bek,
    const float* __restrict__ gv, const float* __restrict__ bev)
{
  __shared__ float lr[8 * 1024], li[8 * 1024];
  __shared__ float2 tw[1024];
  const int tid = threadIdx.x;
  const int dc = blockIdx.x & 7;
  const int bh = blockIdx.x >> 3;
  const int b = bh >> 4, h = bh & 15;
  const int which = blockIdx.y;

  const bf16_t* inR = C6 + which * 2048;
  const bf16_t* inI = inR + 1024;
  const float2* stats = lnst3 + which * 4096;
  const float* gamma = (which == 0) ? gq : (which == 1) ? gk : gv;
  const float* beta  = (which == 0) ? beq : (which == 1) ? bek : bev;
  const float oscale = (which == 0) ? (0.03125f * 0.125f) : 0.03125f;
  const int omode = (which == 0) ? 0 : (which == 1) ? 2 : 1;
  bf16_t* outR = (which == 0) ? Qf : (which == 1) ? Kf : VfT;
  bf16_t* outI = outR + ((which == 2) ? 2048 : 64);

  const bf16_t* bR = inR + (size_t)b * (NN * 6144) + (size_t)h * DHH;
  const bf16_t* bI = inI + (size_t)b * (NN * 6144) + (size_t)h * DHH;
#pragma unroll
  for (int t = tid; t < 1024; t += 512) {
    float ang = -3.14159265358979323846f * (float)t * (1.f / 512.f);
    float sn, cs;
    __sincosf(ang, &sn, &cs);
    tw[t] = make_float2(cs, sn);
  }
  // ---- load + fused LN ----
  {
    float gg[8], bb[8];
#pragma unroll
    for (int ds = 0; ds < 8; ++ds) {
      gg[ds] = gamma[h * DHH + dc * 8 + ds];
      bb[ds] = beta[h * DHH + dc * 8 + ds];
    }
#pragma unroll
    for (int rep = 0; rep < 2; ++rep) {
      int n = tid + rep * 512;
      bf16x8 r8 = *(const bf16x8*)(bR + (size_t)n * 6144 + dc * 8);
      bf16x8 i8 = *(const bf16x8*)(bI + (size_t)n * 6144 + dc * 8);
      float2 stv = stats[b * NN + n];
#pragma unroll
      for (int ds = 0; ds < 8; ++ds) {
        float a = (float)r8[ds], c2 = (float)i8[ds];
        float mag = sqrtf(a * a + c2 * c2);
        float nm = (mag - stv.x) * stv.y * gg[ds] + bb[ds];
        float re, im;
        if (mag > 0.f) { float sc = nm / mag; re = a * sc; im = c2 * sc; }
        else           { re = nm; im = 0.f; }
        int ax = LIDX(ds, n);
        lr[ax] = re;
        li[ax] = im;
      }
    }
  }
  __syncthreads();
  // ---- 5 radix-4 DIF stages (sign = -1) ----
  const int dsub = tid & 7;
  const int jb = tid >> 3;
  int lq2 = 8;
  for (int st = 0; st < 5; ++st) {
    const int qtr = 1 << lq2;
    const int tmul = 1 << (2 * st);
    for (int jt = 0; jt < 4; ++jt) {
      int j = jb + jt * 64;
      int o = j & (qtr - 1);
      int i0 = ((j >> lq2) << (lq2 + 2)) + o;
      int a0 = LIDX(dsub, i0);
      int a1 = LIDX(dsub, i0 + qtr);
      int a2 = LIDX(dsub, i0 + 2 * qtr);
      int a3 = LIDX(dsub, i0 + 3 * qtr);
      float x0r = lr[a0], x0i = li[a0];
      float x1r = lr[a1], x1i = li[a1];
      float x2r = lr[a2], x2i = li[a2];
      float x3r = lr[a3], x3i = li[a3];
      float ar = x0r + x2r, ai2 = x0i + x2i;
      float br = x0r - x2r, bi  = x0i - x2i;
      float cr = x1r + x3r, ci  = x1i + x3i;
      float dr = x1r - x3r, di  = x1i - x3i;
      float2 t1 = tw[o * tmul];
      float2 t2 = tw[2 * o * tmul];
      float2 t3 = tw[3 * o * tmul];
      lr[a0] = ar + cr;  li[a0] = ai2 + ci;
      float u1r = br + di, u1i = bi - dr;     // sign = -1
      lr[a1] = u1r * t1.x - u1i * t1.y;  li[a1] = u1r * t1.y + u1i * t1.x;
      float u2r = ar - cr, u2i = ai2 - ci;
      lr[a2] = u2r * t2.x - u2i * t2.y;  li[a2] = u2r * t2.y + u2i * t2.x;
      float u3r = br - di, u3i = bi + dr;     // sign = -1
      lr[a3] = u3r * t3.x - u3i * t3.y;  li[a3] = u3r * t3.y + u3i * t3.x;
    }
    __syncthreads();
    lq2 -= 2;
  }
  // ---- store (base-4 digit reversal folded into LDS read) ----
  bf16_t* oRb = outR + (size_t)b * 2097152 + (size_t)h * 131072;
  bf16_t* oIb = outI + (size_t)b * 2097152 + (size_t)h * 131072;
#pragma unroll
  for (int rep = 0; rep < 2; ++rep) {
    int n = tid + rep * 512;
    int rv2 = __brev((unsigned)n) >> 22;
    int p = ((rv2 & 0x155) << 1) | ((rv2 >> 1) & 0x155);
    float fr[8], fi[8];
#pragma unroll
    for (int ds = 0; ds < 8; ++ds) {
      fr[ds] = lr[LIDX(ds, p)] * oscale;
      fi[ds] = li[LIDX(ds, p)] * oscale;
    }
    if (omode == 1) {
      size_t tb = (size_t)(n >> 5) * 4096;
#pragma unroll
      for (int ds = 0; ds < 8; ++ds) {
        int dch = dc * 8 + ds;
        size_t ga = tb + (size_t)dch * 32 + ((n & 31) ^ (((dch >> 1) & 3) << 3));
        oRb[ga] = (bf16_t)fr[ds];
        oIb[ga] = (bf16_t)fi[ds];
      }
    } else {
      int cb = dc * 8;
      if (omode == 2) cb = (dc ^ (n & 7)) * 8;
      bf16x8 v0, w0;
#pragma unroll
      for (int k = 0; k < 8; ++k) {
        v0[k] = (bf16_t)fr[k];
        w0[k] = (bf16_t)fi[k];
      }
      size_t gb = (size_t)n * 128 + cb;
      *(bf16x8*)(oRb + gb) = v0;
      *(bf16x8*)(oIb + gb) = w0;
    }
  }
}

// ============================================================
// 1024-pt RADIX-4 DIF FFT v3 — generic (used for the iFFT, imode 1).
// ============================================================
__global__ __launch_bounds__(512) void fft_kernel(
    const bf16_t* __restrict__ inR, const bf16_t* __restrict__ inI,
    bf16_t* __restrict__ outR, bf16_t* __restrict__ outI,
    int in_sb, int in_sh, int in_sn, int in_sd,
    int out_sb, int out_sh, int out_sn,
    float sign, float oscale)
{
  __shared__ float lr[8 * 1024], li[8 * 1024];
  __shared__ float2 tw[1024];
  const int tid = threadIdx.x;
  const int dc = blockIdx.x & 7;
  const int bh = blockIdx.x >> 3;
  const int b = bh >> 4, h = bh & 15;
  const bf16_t* bR = inR + (size_t)b * in_sb + (size_t)h * in_sh;
  const bf16_t* bI = inI + (size_t)b * in_sb + (size_t)h * in_sh;
#pragma unroll
  for (int t = tid; t < 1024; t += 512) {
    float ang = sign * 3.14159265358979323846f * (float)t * (1.f / 512.f);
    float sn, cs;
    __sincosf(ang, &sn, &cs);
    tw[t] = make_float2(cs, sn);
  }
  // n-contiguous input (iFFT from OT [d][N])
  {
    const int ds = tid & 7, nb = tid >> 3;
    const bf16_t* pR = bR + (size_t)(dc * 8 + ds) * in_sd + nb * 16;
    const bf16_t* pI = bI + (size_t)(dc * 8 + ds) * in_sd + nb * 16;
    bf16x8 a0 = *(const bf16x8*)pR, a1 = *(const bf16x8*)(pR + 8);
    bf16x8 b0 = *(const bf16x8*)pI, b1 = *(const bf16x8*)(pI + 8);
#pragma unroll
    for (int k = 0; k < 8; ++k) {
      int c = nb * 16 + k;
      lr[LIDX(ds, c)] = (float)a0[k];       li[LIDX(ds, c)] = (float)b0[k];
      lr[LIDX(ds, c + 8)] = (float)a1[k];   li[LIDX(ds, c + 8)] = (float)b1[k];
    }
  }
  __syncthreads();
  const int dsub = tid & 7;
  const int jb = tid >> 3;
  int lq2 = 8;
  for (int st = 0; st < 5; ++st) {
    const int qtr = 1 << lq2;
    const int tmul = 1 << (2 * st);
    for (int jt = 0; jt < 4; ++jt) {
      int j = jb + jt * 64;
      int o = j & (qtr - 1);
      int i0 = ((j >> lq2) << (lq2 + 2)) + o;
      int a0 = LIDX(dsub, i0);
      int a1 = LIDX(dsub, i0 + qtr);
      int a2 = LIDX(dsub, i0 + 2 * qtr);
      int a3 = LIDX(dsub, i0 + 3 * qtr);
      float x0r = lr[a0], x0i = li[a0];
      float x1r = lr[a1], x1i = li[a1];
      float x2r = lr[a2], x2i = li[a2];
      float x3r = lr[a3], x3i = li[a3];
      float ar = x0r + x2r, ai2 = x0i + x2i;
      float br = x0r - x2r, bi  = x0i - x2i;
      float cr = x1r + x3r, ci  = x1i + x3i;
      float dr = x1r - x3r, di  = x1i - x3i;
      float2 t1 = tw[o * tmul];
      float2 t2 = tw[2 * o * tmul];
      float2 t3 = tw[3 * o * tmul];
      lr[a0] = ar + cr;  li[a0] = ai2 + ci;
      float u1r = br - sign * di, u1i = bi + sign * dr;
      lr[a1] = u1r * t1.x - u1i * t1.y;  li[a1] = u1r * t1.y + u1i * t1.x;
      float u2r = ar - cr, u2i = ai2 - ci;
      lr[a2] = u2r * t2.x - u2i * t2.y;  li[a2] = u2r * t2.y + u2i * t2.x;
      float u3r = br + sign * di, u3i = bi - sign * dr;
      lr[a3] = u3r * t3.x - u3i * t3.y;  li[a3] = u3r * t3.y + u3i * t3.x;
    }
    __syncthreads();
    lq2 -= 2;
  }
  bf16_t* oRb = outR + (size_t)b * out_sb + (size_t)h * out_sh;
  bf16_t* oIb = outI + (size_t)b * out_sb + (size_t)h * out_sh;
#pragma unroll
  for (int rep = 0; rep < 2; ++rep) {
    int n = tid + rep * 512;
    int rv2 = __brev((unsigned)n) >> 22;
    int p = ((rv2 & 0x155) << 1) | ((rv2 >> 1) & 0x155);
    float fr[8], fi[8];
#pragma unroll
    for (int ds = 0; ds < 8; ++ds) {
      fr[ds] = lr[LIDX(ds, p)] * oscale;
      fi[ds] = li[LIDX(ds, p)] * oscale;
    }
    int cb = dc * 8;
    bf16x8 v0, w0;
#pragma unroll
    for (int k = 0; k < 8; ++k) {
      v0[k] = (bf16_t)fr[k];
      w0[k] = (bf16_t)fi[k];
    }
    size_t gb = (size_t)n * out_sn + cb;
    *(bf16x8*)(oRb + gb) = v0;
    *(bf16x8*)(oIb + gb) = w0;
  }
}

// ============================================================
// Flash attention v7 (known-good control).
// ============================================================
__global__ __launch_bounds__(256, 2) void fattn(
    const bf16_t* __restrict__ Qf, const bf16_t* __restrict__ Kfs,
    const bf16_t* __restrict__ Vfs, bf16_t* __restrict__ OT)
{
  __shared__ bf16_t K3[3][4096];
  __shared__ bf16_t V3[3][4096];
  const int tid = threadIdx.x;
  const int w = tid >> 6, l = tid & 63;
  const int lq = l & 31;
  const int h = l >> 5;
  const int i = blockIdx.x;
  const int j = i >> 3;
  const int bh = (i & 7) * 8 + (j >> 3);
  const int q0 = (j & 7) * 128 + w * 32;

  bf16x8 bq[8];
  const bf16_t* qp = Qf + ((size_t)bh * NN + q0 + lq) * 128 + h * 8;
#pragma unroll
  for (int kk = 0; kk < 8; ++kk) bq[kk] = *(const bf16x8*)(qp + kk * 16);

  f32x16 o[4] = {};
  float m = -3e38f, ln = 0.f;

  const bf16_t* kg = Kfs + (size_t)bh * 131072 + w * 1024 + l * 8;
  const bf16_t* vg = Vfs + (size_t)bh * 131072 + w * 1024 + l * 8;
  const int kswz = (lq & 7) << 3;
  const int vswz = ((lq >> 1) & 3) << 3;

#pragma unroll
  for (int tt = 0; tt < 2; ++tt) {
    const bf16_t* kt = kg + (size_t)tt * 4096;
    const bf16_t* vt = vg + (size_t)tt * 4096;
#pragma unroll
    for (int ii = 0; ii < 2; ++ii) {
      __builtin_amdgcn_global_load_lds((const AS1 void*)(kt + ii * 512),
                                       (AS3 void*)&K3[tt][w * 1024 + ii * 512], 16, 0, 0);
      __builtin_amdgcn_global_load_lds((const AS1 void*)(vt + ii * 512),
                                       (AS3 void*)&V3[tt][w * 1024 + ii * 512], 16, 0, 0);
    }
  }
  asm volatile("s_waitcnt vmcnt(4)" ::: "memory");
  __builtin_amdgcn_s_barrier();
  __builtin_amdgcn_sched_barrier(0);

  int cur = 0;
  for (int t = 0; t < 32; ++t) {
    if (t < 30) {
      int nb = cur + 2; if (nb >= 3) nb -= 3;
      const bf16_t* kt = kg + (size_t)(t + 2) * 4096;
      const bf16_t* vt = vg + (size_t)(t + 2) * 4096;
#pragma unroll
      for (int ii = 0; ii < 2; ++ii) {
        __builtin_amdgcn_global_load_lds((const AS1 void*)(kt + ii * 512),
                                         (AS3 void*)&K3[nb][w * 1024 + ii * 512], 16, 0, 0);
        __builtin_amdgcn_global_load_lds((const AS1 void*)(vt + ii * 512),
                                         (AS3 void*)&V3[nb][w * 1024 + ii * 512], 16, 0, 0);
      }
    }

    f32x16 s = {};
#pragma unroll
    for (int kk = 0; kk < 8; ++kk) {
      bf16x8 ak = *(const bf16x8*)&K3[cur][lq * 128 + ((kk * 16 + h * 8) ^ kswz)];
      s = MFMA32(ak, bq[kk], s);
    }

    float pmax = s[0];
#pragma unroll
    for (int r = 1; r < 16; ++r) pmax = fmaxf(pmax, s[r]);
    pmax = fmaxf(pmax, __shfl_xor(pmax, 32));
    if (!__all(pmax - m <= 8.f)) {
      float mnew = fmaxf(m, pmax);
      float alpha = __expf(m - mnew);
      m = mnew;
      ln *= alpha;
#pragma unroll
      for (int db = 0; db < 4; ++db)
#pragma unroll
        for (int r = 0; r < 16; ++r) o[db][r] *= alpha;
    }
    float pf[16];
    float rs = 0.f;
#pragma unroll
    for (int r = 0; r < 16; ++r) { pf[r] = __expf(s[r] - m); rs += pf[r]; }
    rs += __shfl_xor(rs, 32);
    ln += rs;

    unsigned pw[8];
#pragma unroll
    for (int ii = 0; ii < 8; ++ii) pw[ii] = pk2(pf[2 * ii], pf[2 * ii + 1]);
    unsigned r0 = (unsigned)__shfl_xor((int)(h ? pw[0] : pw[2]), 32);
    unsigned r1 = (unsigned)__shfl_xor((int)(h ? pw[1] : pw[3]), 32);
    unsigned r2 = (unsigned)__shfl_xor((int)(h ? pw[4] : pw[6]), 32);
    unsigned r3 = (unsigned)__shfl_xor((int)(h ? pw[5] : pw[7]), 32);
    U16 bp0, bp1;
    bp0.u.x = h ? r0 : pw[0];  bp0.u.y = h ? r1 : pw[1];
    bp0.u.z = h ? pw[2] : r0;  bp0.u.w = h ? pw[3] : r1;
    bp1.u.x = h ? r2 : pw[4];  bp1.u.y = h ? r3 : pw[5];
    bp1.u.z = h ? pw[6] : r2;  bp1.u.w = h ? pw[7] : r3;

#pragma unroll
    for (int db = 0; db < 4; ++db) {
      int r = db * 32 + lq;
      bf16x8 av0 = *(const bf16x8*)&V3[cur][r * 32 + ((h * 8) ^ vswz)];
      bf16x8 av1 = *(const bf16x8*)&V3[cur][r * 32 + ((16 + h * 8) ^ vswz)];
      o[db] = MFMA32(av0, bp0.v, o[db]);
      o[db] = MFMA32(av1, bp1.v, o[db]);
    }

    if (t < 31) {
      if (t < 30) asm volatile("s_waitcnt vmcnt(4)" ::: "memory");
      else        asm volatile("s_waitcnt vmcnt(0)" ::: "memory");
      __builtin_amdgcn_s_barrier();
      __builtin_amdgcn_sched_barrier(0);
    }
    cur = (cur == 2) ? 0 : cur + 1;
  }

  float inv = 1.f / ln;
  const size_t otb = (size_t)bh * 128 * NN + q0 + lq;
#pragma unroll
  for (int db = 0; db < 4; ++db)
#pragma unroll
    for (int r = 0; r < 16; ++r) {
      int dl = (r & 3) + 8 * (r >> 2) + 4 * h;
      OT[otb + (size_t)(db * 32 + dl) * NN] = (bf16_t)(o[db][r] * inv);
    }
}

// ============================================================
// Host-side orchestration
// ============================================================
extern "C" void kernel_launch(void* const* d_in, const int* in_sizes, int n_in,
                              void* d_out, int out_size, void* d_ws, size_t ws_size,
                              hipStream_t stream) {
  const float* xr   = (const float*)d_in[0];
  const float* xi   = (const float*)d_in[1];
  const float* Wqr  = (const float*)d_in[2];
  const float* Wqi  = (const float*)d_in[3];
  const float* bqr  = (const float*)d_in[4];
  const float* bqi  = (const float*)d_in[5];
  const float* Wkr  = (const float*)d_in[6];
  const float* Wki  = (const float*)d_in[7];
  const float* bkr  = (const float*)d_in[8];
  const float* bki  = (const float*)d_in[9];
  const float* Wvr  = (const float*)d_in[10];
  const float* Wvi  = (const float*)d_in[11];
  const float* bvr  = (const float*)d_in[12];
  const float* bvi  = (const float*)d_in[13];
  const float* Wor  = (const float*)d_in[14];
  const float* Woi  = (const float*)d_in[15];
  const float* bor  = (const float*)d_in[16];
  const float* boi  = (const float*)d_in[17];
  const float* gq   = (const float*)d_in[18];
  const float* beq  = (const float*)d_in[19];
  const float* gk   = (const float*)d_in[20];
  const float* bek  = (const float*)d_in[21];
  const float* gv   = (const float*)d_in[22];
  const float* bev  = (const float*)d_in[23];

  char* wp = (char*)d_ws;
  bf16_t* Axaug = (bf16_t*)wp;  wp += (size_t)4096 * 2048 * 2;
  bf16_t* Wcat4 = (bf16_t*)wp;  wp += (size_t)8192 * 2048 * 2;
  float*  bcat4 = (float*)wp;   wp += (size_t)8192 * 4;
  float2* lnst3 = (float2*)wp;  wp += (size_t)3 * 4096 * 8;
  bf16_t* C6    = (bf16_t*)wp;  wp += (size_t)4096 * 6144 * 2;
  bf16_t* Qf    = (bf16_t*)wp;  wp += (size_t)64 * 1024 * 128 * 2;
  bf16_t* Kf    = (bf16_t*)wp;  wp += (size_t)64 * 1024 * 128 * 2;
  bf16_t* VfT   = (bf16_t*)wp;  wp += (size_t)64 * 1024 * 128 * 2;
  bf16_t* OT    = C6;
  bf16_t* Yaug  = Qf;

  const dim3 gQKV(48, 32);
  const dim3 gGemmO(16, 32);
  const int gPackX = (4096 * 2048 / 8) / 256;
  const dim3 gPackW(2048, 4);
  const dim3 gLn(4096, 3);
  const dim3 gFftQKV(512, 3);
  const int gFft = 64 * 8;
  const int gAtt = 64 * 8;

  pack_x<<<gPackX, 256, 0, stream>>>(xr, xi, Axaug);
  pack_w4<<<gPackW, 256, 0, stream>>>(Wqr, Wqi, bqr, bqi,
                                      Wkr, Wki, bkr, bki,
                                      Wvr, Wvi, bvr, bvi,
                                      Wor, Woi, bor, boi,
                                      Wcat4, bcat4);

  gemm_qkv<<<gQKV, 256, 0, stream>>>(Axaug, Wcat4, bcat4, C6);
  ln_stats3<<<gLn, 256, 0, stream>>>(C6, lnst3);

  // ---- all three forward FFTs in one launch ----
  fft_qkv<<<gFftQKV, 512, 0, stream>>>(C6, Qf, Kf, VfT, lnst3,
                                       gq, beq, gk, bek, gv, bev);

  fattn<<<gAtt, 256, 0, stream>>>(Qf, Kf, VfT, OT);

  fft_kernel<<<gFft, 512, 0, stream>>>(OT, OT + (size_t)64 * NN, Yaug, Yaug + 1024,
      16 * 128 * NN, 128 * NN, 1, NN,
      NN * 2048, 64, 2048,
      +1.0f, 0.03125f);

  float* yout = (float*)d_out;
  gemm_bf16<<<gGemmO, 256, 0, stream>>>(Yaug,
      Wcat4 + (size_t)3 * 2048 * 2048, bcat4 + 3 * 2048,
      yout, yout + 1024, 2048);
}

// Round 21
// 390.236 us; speedup vs baseline: 1.0839x; 1.0303x over previous
//
#include <hip/hip_runtime.h>
#include <math.h>

#define BB 4
#define NN 1024
#define DIMM 1024
#define HHH 16
#define DHH 64
#define BN 4096            // B*N rows
#define EPS_LN 1e-6f

typedef __bf16 bf16_t;
typedef __bf16 bf16x8 __attribute__((ext_vector_type(8)));
typedef __bf16 bf16x4 __attribute__((ext_vector_type(4)));
typedef float f32x4 __attribute__((ext_vector_type(4)));
typedef float f32x16 __attribute__((ext_vector_type(16)));
#define MFMA16(a, b, c) __builtin_amdgcn_mfma_f32_16x16x32_bf16(a, b, c, 0, 0, 0)
#define MFMA32(a, b, c) __builtin_amdgcn_mfma_f32_32x32x16_bf16(a, b, c, 0, 0, 0)
#define AS1 __attribute__((address_space(1)))
#define AS3 __attribute__((address_space(3)))

__device__ inline unsigned pk2(float a, float b) {
  union { bf16_t h[2]; unsigned u; } c;
  c.h[0] = (bf16_t)a; c.h[1] = (bf16_t)b;
  return c.u;
}
union U16 { uint4 u; bf16x8 v; };

// ============================================================
// pack_x: Axaug[4096][2048] = bf16([xr | xi])
// ============================================================
__global__ __launch_bounds__(256) void pack_x(
    const float* __restrict__ xr, const float* __restrict__ xi,
    bf16_t* __restrict__ out)
{
  int t = blockIdx.x * 256 + threadIdx.x;
  size_t e = (size_t)t * 8;
  int row = (int)(e >> 11), col = (int)(e & 2047);
  const float* src = (col < 1024) ? (xr + (size_t)row * 1024 + col)
                                  : (xi + (size_t)row * 1024 + col - 1024);
  float4 a = *(const float4*)src;
  float4 b = *(const float4*)(src + 4);
  bf16x8 o;
  o[0] = (bf16_t)a.x; o[1] = (bf16_t)a.y; o[2] = (bf16_t)a.z; o[3] = (bf16_t)a.w;
  o[4] = (bf16_t)b.x; o[5] = (bf16_t)b.y; o[6] = (bf16_t)b.z; o[7] = (bf16_t)b.w;
  *(bf16x8*)(out + e) = o;
}

// ============================================================
// pack_w4: all FOUR projections' augmented weights in ONE launch.
// ============================================================
__global__ __launch_bounds__(256) void pack_w4(
    const float* __restrict__ Wqr, const float* __restrict__ Wqi,
    const float* __restrict__ bqr, const float* __restrict__ bqi,
    const float* __restrict__ Wkr, const float* __restrict__ Wki,
    const float* __restrict__ bkr, const float* __restrict__ bki,
    const float* __restrict__ Wvr, const float* __restrict__ Wvi,
    const float* __restrict__ bvr, const float* __restrict__ bvi,
    const float* __restrict__ Wor, const float* __restrict__ Woi,
    const float* __restrict__ bor, const float* __restrict__ boi,
    bf16_t* __restrict__ Wcat4, float* __restrict__ bcat4)
{
  const int p = blockIdx.y;
  const float* Wr; const float* Wi; const float* br; const float* bi;
  if (p == 0)      { Wr = Wqr; Wi = Wqi; br = bqr; bi = bqi; }
  else if (p == 1) { Wr = Wkr; Wi = Wki; br = bkr; bi = bki; }
  else if (p == 2) { Wr = Wvr; Wi = Wvi; br = bvr; bi = bvi; }
  else             { Wr = Wor; Wi = Woi; br = bor; bi = boi; }
  bf16_t* Wcat = Wcat4 + (size_t)p * 2048 * 2048;
  float*  bcat = bcat4 + (size_t)p * 2048;

  int t = blockIdx.x * 256 + threadIdx.x;
  size_t e = (size_t)t * 8;
  int row = (int)(e >> 11), col = (int)(e & 2047);
  const float* src;
  float sgn = 1.f;
  if (row < 1024) {
    if (col < 1024) src = Wr + (size_t)row * 1024 + col;
    else          { src = Wi + (size_t)row * 1024 + col - 1024; sgn = -1.f; }
  } else {
    int r2 = row - 1024;
    if (col < 1024) src = Wi + (size_t)r2 * 1024 + col;
    else            src = Wr + (size_t)r2 * 1024 + col - 1024;
  }
  float4 a = *(const float4*)src;
  float4 b = *(const float4*)(src + 4);
  bf16x8 o;
  o[0] = (bf16_t)(sgn * a.x); o[1] = (bf16_t)(sgn * a.y);
  o[2] = (bf16_t)(sgn * a.z); o[3] = (bf16_t)(sgn * a.w);
  o[4] = (bf16_t)(sgn * b.x); o[5] = (bf16_t)(sgn * b.y);
  o[6] = (bf16_t)(sgn * b.z); o[7] = (bf16_t)(sgn * b.w);
  *(bf16x8*)(Wcat + e) = o;
  if (e < 2048) {
#pragma unroll
    for (int j = 0; j < 8; ++j) {
      int n = (int)e + j;
      bcat[n] = (n < 1024) ? br[n] : bi[n - 1024];
    }
  }
}

// ============================================================
// Fused QKV GEMM (NT), m97 2-phase known-good, DEFAULT block map
// (T1 swizzle reverted: R20 measured FETCH 107->213 MB, +5.5 us).
// ============================================================
__global__ __launch_bounds__(256) void gemm_qkv(
    const bf16_t* __restrict__ A, const bf16_t* __restrict__ Bt,
    const float* __restrict__ bias, bf16_t* __restrict__ C6)
{
  __shared__ bf16_t sA[128 * 64];
  __shared__ bf16_t sB[128 * 64];
  const int tid = threadIdx.x;
  const int w = tid >> 6, l = tid & 63;
  const int lo4 = l & 15, hi = l >> 4;
  const int wr = w >> 1, wc = w & 1;
  const int row0 = blockIdx.y * 128, col0 = blockIdx.x * 128;

  const int srow = (l >> 3);
  const int scol = (l & 7) * 8;
  const bf16_t* gA[4];
  const bf16_t* gB[4];
#pragma unroll
  for (int i = 0; i < 4; ++i) {
    int r = (w * 4 + i) * 8 + srow;
    gA[i] = A  + (size_t)(row0 + r) * 2048 + scol;
    gB[i] = Bt + (size_t)(col0 + r) * 2048 + scol;
  }

  f32x4 acc[4][4] = {};
  for (int k0 = 0; k0 < 2048; k0 += 64) {
    __syncthreads();
#pragma unroll
    for (int i = 0; i < 4; ++i) {
      __builtin_amdgcn_global_load_lds((const AS1 void*)(gA[i] + k0),
                                       (AS3 void*)&sA[(w * 4 + i) * 512], 16, 0, 0);
      __builtin_amdgcn_global_load_lds((const AS1 void*)(gB[i] + k0),
                                       (AS3 void*)&sB[(w * 4 + i) * 512], 16, 0, 0);
    }
    __syncthreads();
#pragma unroll
    for (int kk = 0; kk < 2; ++kk) {
      bf16x8 am[4], bn[4];
#pragma unroll
      for (int i = 0; i < 4; ++i)
        am[i] = *(const bf16x8*)&sA[(wr * 64 + i * 16 + lo4) * 64 + kk * 32 + hi * 8];
#pragma unroll
      for (int j = 0; j < 4; ++j)
        bn[j] = *(const bf16x8*)&sB[(wc * 64 + j * 16 + lo4) * 64 + kk * 32 + hi * 8];
#pragma unroll
      for (int i = 0; i < 4; ++i)
#pragma unroll
        for (int j = 0; j < 4; ++j)
          acc[i][j] = MFMA16(am[i], bn[j], acc[i][j]);
    }
  }
  const int colg0 = col0 + wc * 64;
#pragma unroll
  for (int i = 0; i < 4; ++i) {
#pragma unroll
    for (int j = 0; j < 4; ++j) {
      float bv = bias[colg0 + j * 16 + lo4];
#pragma unroll
      for (int r = 0; r < 4; ++r) {
        int rowg = row0 + wr * 64 + i * 16 + hi * 4 + r;
        C6[(size_t)rowg * 6144 + colg0 + j * 16 + lo4] = (bf16_t)(acc[i][j][r] + bv);
      }
    }
  }
}

// ============================================================
// O-projection GEMM (known-good, default block map).
// ============================================================
__global__ __launch_bounds__(256) void gemm_bf16(
    const bf16_t* __restrict__ A, const bf16_t* __restrict__ Bt,
    const float* __restrict__ bias,
    float* __restrict__ Cr, float* __restrict__ Ci, int ldc)
{
  __shared__ bf16_t sA[128 * 64];
  __shared__ bf16_t sB[128 * 64];
  const int tid = threadIdx.x;
  const int w = tid >> 6, l = tid & 63;
  const int lo4 = l & 15, hi = l >> 4;
  const int wr = w >> 1, wc = w & 1;
  const int row0 = blockIdx.y * 128, col0 = blockIdx.x * 128;

  const int srow = (l >> 3);
  const int scol = (l & 7) * 8;
  const bf16_t* gA[4];
  const bf16_t* gB[4];
#pragma unroll
  for (int i = 0; i < 4; ++i) {
    int r = (w * 4 + i) * 8 + srow;
    gA[i] = A  + (size_t)(row0 + r) * 2048 + scol;
    gB[i] = Bt + (size_t)(col0 + r) * 2048 + scol;
  }

  f32x4 acc[4][4] = {};
  for (int k0 = 0; k0 < 2048; k0 += 64) {
    __syncthreads();
#pragma unroll
    for (int i = 0; i < 4; ++i) {
      __builtin_amdgcn_global_load_lds((const AS1 void*)(gA[i] + k0),
                                       (AS3 void*)&sA[(w * 4 + i) * 512], 16, 0, 0);
      __builtin_amdgcn_global_load_lds((const AS1 void*)(gB[i] + k0),
                                       (AS3 void*)&sB[(w * 4 + i) * 512], 16, 0, 0);
    }
    __syncthreads();
#pragma unroll
    for (int kk = 0; kk < 2; ++kk) {
      bf16x8 am[4], bn[4];
#pragma unroll
      for (int i = 0; i < 4; ++i)
        am[i] = *(const bf16x8*)&sA[(wr * 64 + i * 16 + lo4) * 64 + kk * 32 + hi * 8];
#pragma unroll
      for (int j = 0; j < 4; ++j)
        bn[j] = *(const bf16x8*)&sB[(wc * 64 + j * 16 + lo4) * 64 + kk * 32 + hi * 8];
#pragma unroll
      for (int i = 0; i < 4; ++i)
#pragma unroll
        for (int j = 0; j < 4; ++j)
          acc[i][j] = MFMA16(am[i], bn[j], acc[i][j]);
    }
  }
  const int colg0 = col0 + wc * 64;
  float* Cp = (colg0 < 1024) ? Cr : Ci;
  const int cb = colg0 & 1023;
#pragma unroll
  for (int i = 0; i < 4; ++i) {
#pragma unroll
    for (int j = 0; j < 4; ++j) {
      float bv = bias[colg0 + j * 16 + lo4];
#pragma unroll
      for (int r = 0; r < 4; ++r) {
        int rowg = row0 + wr * 64 + i * 16 + hi * 4 + r;
        Cp[(size_t)rowg * ldc + cb + j * 16 + lo4] = acc[i][j][r] + bv;
      }
    }
  }
}

// ============================================================
// LN row stats over bf16 C6.
// ============================================================
__global__ __launch_bounds__(256) void ln_stats3(
    const bf16_t* __restrict__ C6, float2* __restrict__ st)
{
  __shared__ float red[8];
  const int row = blockIdx.x;
  const int p = blockIdx.y;
  const int tid = threadIdx.x;
  const bf16_t* pr = C6 + (size_t)row * 6144 + p * 2048;
  const bf16_t* pi = pr + 1024;
  bf16x4 vr = *(const bf16x4*)(pr + tid * 4);
  bf16x4 vi = *(const bf16x4*)(pi + tid * 4);
  float s = 0.f, s2 = 0.f;
#pragma unroll
  for (int t = 0; t < 4; ++t) {
    float a = (float)vr[t], b = (float)vi[t];
    float mg = sqrtf(a * a + b * b);
    s += mg; s2 += mg * mg;
  }
#pragma unroll
  for (int o = 32; o; o >>= 1) { s += __shfl_down(s, o); s2 += __shfl_down(s2, o); }
  if ((tid & 63) == 0) { red[tid >> 6] = s; red[4 + (tid >> 6)] = s2; }
  __syncthreads();
  if (tid == 0) {
    float S = red[0] + red[1] + red[2] + red[3];
    float S2 = red[4] + red[5] + red[6] + red[7];
    float mean = S * (1.f / DIMM);
    float var = S2 * (1.f / DIMM) - mean * mean;
    st[(size_t)p * 4096 + row] = make_float2(mean, rsqrtf(var + EPS_LN));
  }
}

#define LIDX(d_, c_) (((d_) << 10) + ((c_) ^ (((c_) >> 5) & 31) ^ (((d_) & 7) << 2)))

// ============================================================
// fft_qkv: all THREE forward FFTs in ONE launch, grid (512, 3)
// (kept from R20: the merge was the winning half, ~8 us).
// ============================================================
__global__ __launch_bounds__(512) void fft_qkv(
    const bf16_t* __restrict__ C6,
    bf16_t* __restrict__ Qf, bf16_t* __restrict__ Kf, bf16_t* __restrict__ VfT,
    const float2* __restrict__ lnst3,
    const float* __restrict__ gq, const float* __restrict__ beq,
    const float* __restrict__ gk, const float* __restrict__ bek,
    const float* __restrict__ gv, const float* __restrict__ bev)
{
  __shared__ float lr[8 * 1024], li[8 * 1024];
  __shared__ float2 tw[1024];
  const int tid = threadIdx.x;
  const int dc = blockIdx.x & 7;
  const int bh = blockIdx.x >> 3;
  const int b = bh >> 4, h = bh & 15;
  const int which = blockIdx.y;

  const bf16_t* inR = C6 + which * 2048;
  const bf16_t* inI = inR + 1024;
  const float2* stats = lnst3 + which * 4096;
  const float* gamma = (which == 0) ? gq : (which == 1) ? gk : gv;
  const float* beta  = (which == 0) ? beq : (which == 1) ? bek : bev;
  const float oscale = (which == 0) ? (0.03125f * 0.125f) : 0.03125f;
  const int omode = (which == 0) ? 0 : (which == 1) ? 2 : 1;
  bf16_t* outR = (which == 0) ? Qf : (which == 1) ? Kf : VfT;
  bf16_t* outI = outR + ((which == 2) ? 2048 : 64);

  const bf16_t* bR = inR + (size_t)b * (NN * 6144) + (size_t)h * DHH;
  const bf16_t* bI = inI + (size_t)b * (NN * 6144) + (size_t)h * DHH;
#pragma unroll
  for (int t = tid; t < 1024; t += 512) {
    float ang = -3.14159265358979323846f * (float)t * (1.f / 512.f);
    float sn, cs;
    __sincosf(ang, &sn, &cs);
    tw[t] = make_float2(cs, sn);
  }
  // ---- load + fused LN ----
  {
    float gg[8], bb[8];
#pragma unroll
    for (int ds = 0; ds < 8; ++ds) {
      gg[ds] = gamma[h * DHH + dc * 8 + ds];
      bb[ds] = beta[h * DHH + dc * 8 + ds];
    }
#pragma unroll
    for (int rep = 0; rep < 2; ++rep) {
      int n = tid + rep * 512;
      bf16x8 r8 = *(const bf16x8*)(bR + (size_t)n * 6144 + dc * 8);
      bf16x8 i8 = *(const bf16x8*)(bI + (size_t)n * 6144 + dc * 8);
      float2 stv = stats[b * NN + n];
#pragma unroll
      for (int ds = 0; ds < 8; ++ds) {
        float a = (float)r8[ds], c2 = (float)i8[ds];
        float mag = sqrtf(a * a + c2 * c2);
        float nm = (mag - stv.x) * stv.y * gg[ds] + bb[ds];
        float re, im;
        if (mag > 0.f) { float sc = nm / mag; re = a * sc; im = c2 * sc; }
        else           { re = nm; im = 0.f; }
        int ax = LIDX(ds, n);
        lr[ax] = re;
        li[ax] = im;
      }
    }
  }
  __syncthreads();
  // ---- 5 radix-4 DIF stages (sign = -1) ----
  const int dsub = tid & 7;
  const int jb = tid >> 3;
  int lq2 = 8;
  for (int st = 0; st < 5; ++st) {
    const int qtr = 1 << lq2;
    const int tmul = 1 << (2 * st);
    for (int jt = 0; jt < 4; ++jt) {
      int j = jb + jt * 64;
      int o = j & (qtr - 1);
      int i0 = ((j >> lq2) << (lq2 + 2)) + o;
      int a0 = LIDX(dsub, i0);
      int a1 = LIDX(dsub, i0 + qtr);
      int a2 = LIDX(dsub, i0 + 2 * qtr);
      int a3 = LIDX(dsub, i0 + 3 * qtr);
      float x0r = lr[a0], x0i = li[a0];
      float x1r = lr[a1], x1i = li[a1];
      float x2r = lr[a2], x2i = li[a2];
      float x3r = lr[a3], x3i = li[a3];
      float ar = x0r + x2r, ai2 = x0i + x2i;
      float br = x0r - x2r, bi  = x0i - x2i;
      float cr = x1r + x3r, ci  = x1i + x3i;
      float dr = x1r - x3r, di  = x1i - x3i;
      float2 t1 = tw[o * tmul];
      float2 t2 = tw[2 * o * tmul];
      float2 t3 = tw[3 * o * tmul];
      lr[a0] = ar + cr;  li[a0] = ai2 + ci;
      float u1r = br + di, u1i = bi - dr;     // sign = -1
      lr[a1] = u1r * t1.x - u1i * t1.y;  li[a1] = u1r * t1.y + u1i * t1.x;
      float u2r = ar - cr, u2i = ai2 - ci;
      lr[a2] = u2r * t2.x - u2i * t2.y;  li[a2] = u2r * t2.y + u2i * t2.x;
      float u3r = br - di, u3i = bi + dr;     // sign = -1
      lr[a3] = u3r * t3.x - u3i * t3.y;  li[a3] = u3r * t3.y + u3i * t3.x;
    }
    __syncthreads();
    lq2 -= 2;
  }
  // ---- store (base-4 digit reversal folded into LDS read) ----
  bf16_t* oRb = outR + (size_t)b * 2097152 + (size_t)h * 131072;
  bf16_t* oIb = outI + (size_t)b * 2097152 + (size_t)h * 131072;
#pragma unroll
  for (int rep = 0; rep < 2; ++rep) {
    int n = tid + rep * 512;
    int rv2 = __brev((unsigned)n) >> 22;
    int p = ((rv2 & 0x155) << 1) | ((rv2 >> 1) & 0x155);
    float fr[8], fi[8];
#pragma unroll
    for (int ds = 0; ds < 8; ++ds) {
      fr[ds] = lr[LIDX(ds, p)] * oscale;
      fi[ds] = li[LIDX(ds, p)] * oscale;
    }
    if (omode == 1) {
      size_t tb = (size_t)(n >> 5) * 4096;
#pragma unroll
      for (int ds = 0; ds < 8; ++ds) {
        int dch = dc * 8 + ds;
        size_t ga = tb + (size_t)dch * 32 + ((n & 31) ^ (((dch >> 1) & 3) << 3));
        oRb[ga] = (bf16_t)fr[ds];
        oIb[ga] = (bf16_t)fi[ds];
      }
    } else {
      int cb = dc * 8;
      if (omode == 2) cb = (dc ^ (n & 7)) * 8;
      bf16x8 v0, w0;
#pragma unroll
      for (int k = 0; k < 8; ++k) {
        v0[k] = (bf16_t)fr[k];
        w0[k] = (bf16_t)fi[k];
      }
      size_t gb = (size_t)n * 128 + cb;
      *(bf16x8*)(oRb + gb) = v0;
      *(bf16x8*)(oIb + gb) = w0;
    }
  }
}

// ============================================================
// 1024-pt RADIX-4 DIF FFT — generic (iFFT, n-contiguous input).
// ============================================================
__global__ __launch_bounds__(512) void fft_kernel(
    const bf16_t* __restrict__ inR, const bf16_t* __restrict__ inI,
    bf16_t* __restrict__ outR, bf16_t* __restrict__ outI,
    int in_sb, int in_sh, int in_sn, int in_sd,
    int out_sb, int out_sh, int out_sn,
    float sign, float oscale)
{
  __shared__ float lr[8 * 1024], li[8 * 1024];
  __shared__ float2 tw[1024];
  const int tid = threadIdx.x;
  const int dc = blockIdx.x & 7;
  const int bh = blockIdx.x >> 3;
  const int b = bh >> 4, h = bh & 15;
  const bf16_t* bR = inR + (size_t)b * in_sb + (size_t)h * in_sh;
  const bf16_t* bI = inI + (size_t)b * in_sb + (size_t)h * in_sh;
#pragma unroll
  for (int t = tid; t < 1024; t += 512) {
    float ang = sign * 3.14159265358979323846f * (float)t * (1.f / 512.f);
    float sn, cs;
    __sincosf(ang, &sn, &cs);
    tw[t] = make_float2(cs, sn);
  }
  {
    const int ds = tid & 7, nb = tid >> 3;
    const bf16_t* pR = bR + (size_t)(dc * 8 + ds) * in_sd + nb * 16;
    const bf16_t* pI = bI + (size_t)(dc * 8 + ds) * in_sd + nb * 16;
    bf16x8 a0 = *(const bf16x8*)pR, a1 = *(const bf16x8*)(pR + 8);
    bf16x8 b0 = *(const bf16x8*)pI, b1 = *(const bf16x8*)(pI + 8);
#pragma unroll
    for (int k = 0; k < 8; ++k) {
      int c = nb * 16 + k;
      lr[LIDX(ds, c)] = (float)a0[k];       li[LIDX(ds, c)] = (float)b0[k];
      lr[LIDX(ds, c + 8)] = (float)a1[k];   li[LIDX(ds, c + 8)] = (float)b1[k];
    }
  }
  __syncthreads();
  const int dsub = tid & 7;
  const int jb = tid >> 3;
  int lq2 = 8;
  for (int st = 0; st < 5; ++st) {
    const int qtr = 1 << lq2;
    const int tmul = 1 << (2 * st);
    for (int jt = 0; jt < 4; ++jt) {
      int j = jb + jt * 64;
      int o = j & (qtr - 1);
      int i0 = ((j >> lq2) << (lq2 + 2)) + o;
      int a0 = LIDX(dsub, i0);
      int a1 = LIDX(dsub, i0 + qtr);
      int a2 = LIDX(dsub, i0 + 2 * qtr);
      int a3 = LIDX(dsub, i0 + 3 * qtr);
      float x0r = lr[a0], x0i = li[a0];
      float x1r = lr[a1], x1i = li[a1];
      float x2r = lr[a2], x2i = li[a2];
      float x3r = lr[a3], x3i = li[a3];
      float ar = x0r + x2r, ai2 = x0i + x2i;
      float br = x0r - x2r, bi  = x0i - x2i;
      float cr = x1r + x3r, ci  = x1i + x3i;
      float dr = x1r - x3r, di  = x1i - x3i;
      float2 t1 = tw[o * tmul];
      float2 t2 = tw[2 * o * tmul];
      float2 t3 = tw[3 * o * tmul];
      lr[a0] = ar + cr;  li[a0] = ai2 + ci;
      float u1r = br - sign * di, u1i = bi + sign * dr;
      lr[a1] = u1r * t1.x - u1i * t1.y;  li[a1] = u1r * t1.y + u1i * t1.x;
      float u2r = ar - cr, u2i = ai2 - ci;
      lr[a2] = u2r * t2.x - u2i * t2.y;  li[a2] = u2r * t2.y + u2i * t2.x;
      float u3r = br + sign * di, u3i = bi - sign * dr;
      lr[a3] = u3r * t3.x - u3i * t3.y;  li[a3] = u3r * t3.y + u3i * t3.x;
    }
    __syncthreads();
    lq2 -= 2;
  }
  bf16_t* oRb = outR + (size_t)b * out_sb + (size_t)h * out_sh;
  bf16_t* oIb = outI + (size_t)b * out_sb + (size_t)h * out_sh;
#pragma unroll
  for (int rep = 0; rep < 2; ++rep) {
    int n = tid + rep * 512;
    int rv2 = __brev((unsigned)n) >> 22;
    int p = ((rv2 & 0x155) << 1) | ((rv2 >> 1) & 0x155);
    float fr[8], fi[8];
#pragma unroll
    for (int ds = 0; ds < 8; ++ds) {
      fr[ds] = lr[LIDX(ds, p)] * oscale;
      fi[ds] = li[LIDX(ds, p)] * oscale;
    }
    int cb = dc * 8;
    bf16x8 v0, w0;
#pragma unroll
    for (int k = 0; k < 8; ++k) {
      v0[k] = (bf16_t)fr[k];
      w0[k] = (bf16_t)fi[k];
    }
    size_t gb = (size_t)n * out_sn + cb;
    *(bf16x8*)(oRb + gb) = v0;
    *(bf16x8*)(oIb + gb) = w0;
  }
}

// ============================================================
// Flash attention v7 (known-good control).
// ============================================================
__global__ __launch_bounds__(256, 2) void fattn(
    const bf16_t* __restrict__ Qf, const bf16_t* __restrict__ Kfs,
    const bf16_t* __restrict__ Vfs, bf16_t* __restrict__ OT)
{
  __shared__ bf16_t K3[3][4096];
  __shared__ bf16_t V3[3][4096];
  const int tid = threadIdx.x;
  const int w = tid >> 6, l = tid & 63;
  const int lq = l & 31;
  const int h = l >> 5;
  const int i = blockIdx.x;
  const int j = i >> 3;
  const int bh = (i & 7) * 8 + (j >> 3);
  const int q0 = (j & 7) * 128 + w * 32;

  bf16x8 bq[8];
  const bf16_t* qp = Qf + ((size_t)bh * NN + q0 + lq) * 128 + h * 8;
#pragma unroll
  for (int kk = 0; kk < 8; ++kk) bq[kk] = *(const bf16x8*)(qp + kk * 16);

  f32x16 o[4] = {};
  float m = -3e38f, ln = 0.f;

  const bf16_t* kg = Kfs + (size_t)bh * 131072 + w * 1024 + l * 8;
  const bf16_t* vg = Vfs + (size_t)bh * 131072 + w * 1024 + l * 8;
  const int kswz = (lq & 7) << 3;
  const int vswz = ((lq >> 1) & 3) << 3;

#pragma unroll
  for (int tt = 0; tt < 2; ++tt) {
    const bf16_t* kt = kg + (size_t)tt * 4096;
    const bf16_t* vt = vg + (size_t)tt * 4096;
#pragma unroll
    for (int ii = 0; ii < 2; ++ii) {
      __builtin_amdgcn_global_load_lds((const AS1 void*)(kt + ii * 512),
                                       (AS3 void*)&K3[tt][w * 1024 + ii * 512], 16, 0, 0);
      __builtin_amdgcn_global_load_lds((const AS1 void*)(vt + ii * 512),
                                       (AS3 void*)&V3[tt][w * 1024 + ii * 512], 16, 0, 0);
    }
  }
  asm volatile("s_waitcnt vmcnt(4)" ::: "memory");
  __builtin_amdgcn_s_barrier();
  __builtin_amdgcn_sched_barrier(0);

  int cur = 0;
  for (int t = 0; t < 32; ++t) {
    if (t < 30) {
      int nb = cur + 2; if (nb >= 3) nb -= 3;
      const bf16_t* kt = kg + (size_t)(t + 2) * 4096;
      const bf16_t* vt = vg + (size_t)(t + 2) * 4096;
#pragma unroll
      for (int ii = 0; ii < 2; ++ii) {
        __builtin_amdgcn_global_load_lds((const AS1 void*)(kt + ii * 512),
                                         (AS3 void*)&K3[nb][w * 1024 + ii * 512], 16, 0, 0);
        __builtin_amdgcn_global_load_lds((const AS1 void*)(vt + ii * 512),
                                         (AS3 void*)&V3[nb][w * 1024 + ii * 512], 16, 0, 0);
      }
    }

    f32x16 s = {};
#pragma unroll
    for (int kk = 0; kk < 8; ++kk) {
      bf16x8 ak = *(const bf16x8*)&K3[cur][lq * 128 + ((kk * 16 + h * 8) ^ kswz)];
      s = MFMA32(ak, bq[kk], s);
    }

    float pmax = s[0];
#pragma unroll
    for (int r = 1; r < 16; ++r) pmax = fmaxf(pmax, s[r]);
    pmax = fmaxf(pmax, __shfl_xor(pmax, 32));
    if (!__all(pmax - m <= 8.f)) {
      float mnew = fmaxf(m, pmax);
      float alpha = __expf(m - mnew);
      m = mnew;
      ln *= alpha;
#pragma unroll
      for (int db = 0; db < 4; ++db)
#pragma unroll
        for (int r = 0; r < 16; ++r) o[db][r] *= alpha;
    }
    float pf[16];
    float rs = 0.f;
#pragma unroll
    for (int r = 0; r < 16; ++r) { pf[r] = __expf(s[r] - m); rs += pf[r]; }
    rs += __shfl_xor(rs, 32);
    ln += rs;

    unsigned pw[8];
#pragma unroll
    for (int ii = 0; ii < 8; ++ii) pw[ii] = pk2(pf[2 * ii], pf[2 * ii + 1]);
    unsigned r0 = (unsigned)__shfl_xor((int)(h ? pw[0] : pw[2]), 32);
    unsigned r1 = (unsigned)__shfl_xor((int)(h ? pw[1] : pw[3]), 32);
    unsigned r2 = (unsigned)__shfl_xor((int)(h ? pw[4] : pw[6]), 32);
    unsigned r3 = (unsigned)__shfl_xor((int)(h ? pw[5] : pw[7]), 32);
    U16 bp0, bp1;
    bp0.u.x = h ? r0 : pw[0];  bp0.u.y = h ? r1 : pw[1];
    bp0.u.z = h ? pw[2] : r0;  bp0.u.w = h ? pw[3] : r1;
    bp1.u.x = h ? r2 : pw[4];  bp1.u.y = h ? r3 : pw[5];
    bp1.u.z = h ? pw[6] : r2;  bp1.u.w = h ? pw[7] : r3;

#pragma unroll
    for (int db = 0; db < 4; ++db) {
      int r = db * 32 + lq;
      bf16x8 av0 = *(const bf16x8*)&V3[cur][r * 32 + ((h * 8) ^ vswz)];
      bf16x8 av1 = *(const bf16x8*)&V3[cur][r * 32 + ((16 + h * 8) ^ vswz)];
      o[db] = MFMA32(av0, bp0.v, o[db]);
      o[db] = MFMA32(av1, bp1.v, o[db]);
    }

    if (t < 31) {
      if (t < 30) asm volatile("s_waitcnt vmcnt(4)" ::: "memory");
      else        asm volatile("s_waitcnt vmcnt(0)" ::: "memory");
      __builtin_amdgcn_s_barrier();
      __builtin_amdgcn_sched_barrier(0);
    }
    cur = (cur == 2) ? 0 : cur + 1;
  }

  float inv = 1.f / ln;
  const size_t otb = (size_t)bh * 128 * NN + q0 + lq;
#pragma unroll
  for (int db = 0; db < 4; ++db)
#pragma unroll
    for (int r = 0; r < 16; ++r) {
      int dl = (r & 3) + 8 * (r >> 2) + 4 * h;
      OT[otb + (size_t)(db * 32 + dl) * NN] = (bf16_t)(o[db][r] * inv);
    }
}

// ============================================================
// Host-side orchestration
// ============================================================
extern "C" void kernel_launch(void* const* d_in, const int* in_sizes, int n_in,
                              void* d_out, int out_size, void* d_ws, size_t ws_size,
                              hipStream_t stream) {
  const float* xr   = (const float*)d_in[0];
  const float* xi   = (const float*)d_in[1];
  const float* Wqr  = (const float*)d_in[2];
  const float* Wqi  = (const float*)d_in[3];
  const float* bqr  = (const float*)d_in[4];
  const float* bqi  = (const float*)d_in[5];
  const float* Wkr  = (const float*)d_in[6];
  const float* Wki  = (const float*)d_in[7];
  const float* bkr  = (const float*)d_in[8];
  const float* bki  = (const float*)d_in[9];
  const float* Wvr  = (const float*)d_in[10];
  const float* Wvi  = (const float*)d_in[11];
  const float* bvr  = (const float*)d_in[12];
  const float* bvi  = (const float*)d_in[13];
  const float* Wor  = (const float*)d_in[14];
  const float* Woi  = (const float*)d_in[15];
  const float* bor  = (const float*)d_in[16];
  const float* boi  = (const float*)d_in[17];
  const float* gq   = (const float*)d_in[18];
  const float* beq  = (const float*)d_in[19];
  const float* gk   = (const float*)d_in[20];
  const float* bek  = (const float*)d_in[21];
  const float* gv   = (const float*)d_in[22];
  const float* bev  = (const float*)d_in[23];

  char* wp = (char*)d_ws;
  bf16_t* Axaug = (bf16_t*)wp;  wp += (size_t)4096 * 2048 * 2;
  bf16_t* Wcat4 = (bf16_t*)wp;  wp += (size_t)8192 * 2048 * 2;
  float*  bcat4 = (float*)wp;   wp += (size_t)8192 * 4;
  float2* lnst3 = (float2*)wp;  wp += (size_t)3 * 4096 * 8;
  bf16_t* C6    = (bf16_t*)wp;  wp += (size_t)4096 * 6144 * 2;
  bf16_t* Qf    = (bf16_t*)wp;  wp += (size_t)64 * 1024 * 128 * 2;
  bf16_t* Kf    = (bf16_t*)wp;  wp += (size_t)64 * 1024 * 128 * 2;
  bf16_t* VfT   = (bf16_t*)wp;  wp += (size_t)64 * 1024 * 128 * 2;
  bf16_t* OT    = C6;
  bf16_t* Yaug  = Qf;

  const dim3 gQKV(48, 32);
  const dim3 gGemmO(16, 32);
  const int gPackX = (4096 * 2048 / 8) / 256;
  const dim3 gPackW(2048, 4);
  const dim3 gLn(4096, 3);
  const dim3 gFftQKV(512, 3);
  const int gFft = 64 * 8;
  const int gAtt = 64 * 8;

  pack_x<<<gPackX, 256, 0, stream>>>(xr, xi, Axaug);
  pack_w4<<<gPackW, 256, 0, stream>>>(Wqr, Wqi, bqr, bqi,
                                      Wkr, Wki, bkr, bki,
                                      Wvr, Wvi, bvr, bvi,
                                      Wor, Woi, bor, boi,
                                      Wcat4, bcat4);

  gemm_qkv<<<gQKV, 256, 0, stream>>>(Axaug, Wcat4, bcat4, C6);
  ln_stats3<<<gLn, 256, 0, stream>>>(C6, lnst3);

  fft_qkv<<<gFftQKV, 512, 0, stream>>>(C6, Qf, Kf, VfT, lnst3,
                                       gq, beq, gk, bek, gv, bev);

  fattn<<<gAtt, 256, 0, stream>>>(Qf, Kf, VfT, OT);

  fft_kernel<<<gFft, 512, 0, stream>>>(OT, OT + (size_t)64 * NN, Yaug, Yaug + 1024,
      16 * 128 * NN, 128 * NN, 1, NN,
      NN * 2048, 64, 2048,
      +1.0f, 0.03125f);

  float* yout = (float*)d_out;
  gemm_bf16<<<gGemmO, 256, 0, stream>>>(Yaug,
      Wcat4 + (size_t)3 * 2048 * 2048, bcat4 + 3 * 2048,
      yout, yout + 1024, 2048);
}